// Round 12
// baseline (507.765 us; speedup 1.0000x reference)
//
#include <hip/hip_runtime.h>
#include <cmath>

#define DEVINL __device__ __forceinline__

typedef unsigned short ushort_t;
typedef unsigned int uint_t;

constexpr int Bb   = 2;
constexpr int Ss   = 2048;
constexpr int S1   = 2049;
constexpr int DIN  = 1024;
constexpr int Dd   = 512;
constexpr int Hh   = 8;
constexpr int FF   = 2048;
constexpr int Ee   = 6;
constexpr int NCc  = 2;
constexpr int CAP  = 341;
constexpr int NTOK = Bb * Ss;     // 4096
constexpr int RR   = Bb * S1;     // 4098
constexpr int MOE_ROWS = Bb * CAP; // 682

typedef __attribute__((ext_vector_type(4))) float f32x4;
typedef __attribute__((ext_vector_type(8))) short bf16x8;

DEVINL float geluf(float x) { return 0.5f * x * (1.0f + erff(x * 0.7071067811865476f)); }

DEVINL ushort_t f2bf(float f) {
  uint_t u = __float_as_uint(f);
  u += 0x7FFFu + ((u >> 16) & 1u);
  return (ushort_t)(u >> 16);
}
DEVINL float bf2f(ushort_t u) { return __uint_as_float((uint_t)u << 16); }

// async global->LDS, 16B per lane; LDS dest = wave-uniform base + lane*16,
// global src per-lane (pre-swizzled).  [m97/m104/m173 pattern]
DEVINL void glds16(const ushort_t* g, void* lds) {
  __builtin_amdgcn_global_load_lds(
      (const __attribute__((address_space(1))) void*)g,
      (__attribute__((address_space(3))) void*)lds, 16, 0, 0);
}

DEVINL float wsum(float v) {
#pragma unroll
  for (int off = 32; off; off >>= 1) v += __shfl_xor(v, off);
  return v;
}
DEVINL float bsum(float v, float* red) {
  v = wsum(v);
  int w = threadIdx.x >> 6;
  if ((threadIdx.x & 63) == 0) red[w] = v;
  __syncthreads();
  float r = red[0] + red[1] + red[2] + red[3];
  __syncthreads();
  return r;
}

// ---------------- batched fp32->bf16 cast: x + 4 attn weights ---------------
constexpr int C5_N0 = NTOK * DIN / 8;          // 524288
constexpr int C5_N1 = 3 * Dd * Dd / 8;         // 98304
constexpr int C5_N2 = Dd * Dd / 8;             // 32768
constexpr int C5_T  = C5_N0 + 2 * C5_N1 + 2 * C5_N2;  // 786432
__global__ __launch_bounds__(256) void cast5_kernel(const float* __restrict__ s0, ushort_t* __restrict__ d0,
                                                    const float* __restrict__ s1, ushort_t* __restrict__ d1,
                                                    const float* __restrict__ s2, ushort_t* __restrict__ d2,
                                                    const float* __restrict__ s3, ushort_t* __restrict__ d3,
                                                    const float* __restrict__ s4, ushort_t* __restrict__ d4) {
  int i = blockIdx.x * 256 + threadIdx.x;
  if (i >= C5_T) return;
  const float* src; ushort_t* dst; int off;
  if (i < C5_N0) { src = s0; dst = d0; off = i; }
  else if (i < C5_N0 + C5_N1) { src = s1; dst = d1; off = i - C5_N0; }
  else if (i < C5_N0 + C5_N1 + C5_N2) { src = s2; dst = d2; off = i - C5_N0 - C5_N1; }
  else if (i < C5_N0 + 2 * C5_N1 + C5_N2) { src = s3; dst = d3; off = i - C5_N0 - C5_N1 - C5_N2; }
  else { src = s4; dst = d4; off = i - C5_N0 - 2 * C5_N1 - C5_N2; }
  float4 a = *(const float4*)(src + (size_t)off * 8);
  float4 b = *(const float4*)(src + (size_t)off * 8 + 4);
  bf16x8 v;
  v[0] = (short)f2bf(a.x); v[1] = (short)f2bf(a.y);
  v[2] = (short)f2bf(a.z); v[3] = (short)f2bf(a.w);
  v[4] = (short)f2bf(b.x); v[5] = (short)f2bf(b.y);
  v[6] = (short)f2bf(b.z); v[7] = (short)f2bf(b.w);
  *(bf16x8*)(dst + (size_t)off * 8) = v;
}

// KxN fp32 -> NxK bf16 (batched over z)
__global__ __launch_bounds__(256) void tpose_cast_kernel(const float* __restrict__ in,
                                                         ushort_t* __restrict__ outp,
                                                         int K, int N) {
  __shared__ float t[64][65];
  const int z = blockIdx.z;
  const float* src = in + (size_t)z * K * N;
  ushort_t* dst = outp + (size_t)z * K * N;
  const int k0 = blockIdx.x * 64, n0 = blockIdx.y * 64;
  const int tx = threadIdx.x & 15, ty = threadIdx.x >> 4;
#pragma unroll
  for (int p = 0; p < 4; ++p) {
    int k = ty + p * 16;
    float4 v = *(const float4*)(src + (size_t)(k0 + k) * N + n0 + tx * 4);
    t[k][tx * 4 + 0] = v.x; t[k][tx * 4 + 1] = v.y;
    t[k][tx * 4 + 2] = v.z; t[k][tx * 4 + 3] = v.w;
  }
  __syncthreads();
#pragma unroll
  for (int p = 0; p < 4; ++p) {
    int n = ty + p * 16;
    uint_t lo = (uint_t)f2bf(t[tx * 4 + 0][n]) | ((uint_t)f2bf(t[tx * 4 + 1][n]) << 16);
    uint_t hi = (uint_t)f2bf(t[tx * 4 + 2][n]) | ((uint_t)f2bf(t[tx * 4 + 3][n]) << 16);
    *(uint2*)(dst + (size_t)(n0 + n) * K + k0 + tx * 4) = make_uint2(lo, hi);
  }
}

// ---------------- labels: cosine-sim argmax over 4 protos -------------------
__global__ __launch_bounds__(256) void labels_kernel(const float* __restrict__ x,
                                                     const float* __restrict__ protos,
                                                     int* __restrict__ lbl) {
  int t = blockIdx.x * 4 + (threadIdx.x >> 6);
  int lane = threadIdx.x & 63;
  if (t >= NTOK) return;
  const float* xr = x + (size_t)t * DIN;
  float xv[16];
  float ss = 0.f;
#pragma unroll
  for (int i = 0; i < 16; ++i) { xv[i] = xr[lane + 64 * i]; ss += xv[i] * xv[i]; }
  ss = wsum(ss);
  float nx = sqrtf(ss) + 1e-8f;
  float best = -2e30f; int bi = 0;
  for (int p = 0; p < 4; ++p) {
    const float* pr = protos + (size_t)p * DIN;
    float dp = 0.f, pp = 0.f;
#pragma unroll
    for (int i = 0; i < 16; ++i) { float v = pr[lane + 64 * i]; dp += v * xv[i]; pp += v * v; }
    dp = wsum(dp); pp = wsum(pp);
    float sim = dp / (nx * (sqrtf(pp) + 1e-8f));
    if (sim > best) { best = sim; bi = p; }
  }
  if (lane == 0) lbl[t] = bi;
}

// ================= bf16 MFMA GEMM, global_load_lds staging ==================
// C(MxN) bf16 = act(A @ B^T + bias) [+ res].  A bf16 MxK row-major,
// B bf16 NxK row-major.  SHIFT: C row remap row -> row + row/2048 + 1.
// BMT in {64,128}: tile BMTx128x64, 4 waves 2x2, wave tile (BMT/2)x64.
template <bool ACT, bool SHIFT, int BMT>
__global__ __launch_bounds__(256) void mgemm_kernel(const ushort_t* __restrict__ A, int lda,
                                                    const ushort_t* __restrict__ Bw, int ldb,
                                                    const float* __restrict__ bias,
                                                    const ushort_t* __restrict__ res,
                                                    ushort_t* __restrict__ C, int ldc,
                                                    int M, int N, int K) {
  constexpr int MI = BMT / 32;              // A frags per wave (2 or 4)
  __shared__ ushort_t As[BMT * 64];
  __shared__ ushort_t Bs[128 * 64];
  const int tid = threadIdx.x;
  const int l = tid & 63, l15 = l & 15, lg = l >> 4;
  const int w = tid >> 6;
  const int wm = w >> 1, wn = w & 1;
  const int bm = blockIdx.x * BMT, bn = blockIdx.y * 128;
  const int srowA = w * (BMT / 4) + (l >> 3);
  const int srowB = w * 32 + (l >> 3);
  const int scc = ((l & 7) ^ (l >> 3)) * 8;

  f32x4 acc[MI][4];
#pragma unroll
  for (int i = 0; i < MI; ++i)
#pragma unroll
    for (int j = 0; j < 4; ++j) acc[i][j] = (f32x4){0.f, 0.f, 0.f, 0.f};

  const ushort_t* agp[MI];
  const ushort_t* bgp[4];
#pragma unroll
  for (int j = 0; j < MI; ++j) {
    int ar = bm + srowA + j * 8; if (ar > M - 1) ar = M - 1;
    agp[j] = A + (size_t)ar * lda + scc;
  }
#pragma unroll
  for (int j = 0; j < 4; ++j)
    bgp[j] = Bw + (size_t)(bn + srowB + j * 8) * ldb + scc;

  for (int k0 = 0; k0 < K; k0 += 64) {
#pragma unroll
    for (int j = 0; j < MI; ++j)
      glds16(agp[j] + k0, (char*)As + w * (BMT * 32) + j * 1024);
#pragma unroll
    for (int j = 0; j < 4; ++j)
      glds16(bgp[j] + k0, (char*)Bs + w * 4096 + j * 1024);
    __syncthreads();
#pragma unroll
    for (int kc = 0; kc < 2; ++kc) {
      bf16x8 af[MI], bfr[4];
#pragma unroll
      for (int mi = 0; mi < MI; ++mi) {
        int row = wm * (BMT / 2) + mi * 16 + l15;
        af[mi] = *(const bf16x8*)((const char*)As +
                   ((row * 128 + (kc * 32 + lg * 8) * 2) ^ ((row & 7) << 4)));
      }
#pragma unroll
      for (int ni = 0; ni < 4; ++ni) {
        int row = wn * 64 + ni * 16 + l15;
        bfr[ni] = *(const bf16x8*)((const char*)Bs +
                   ((row * 128 + (kc * 32 + lg * 8) * 2) ^ ((row & 7) << 4)));
      }
#pragma unroll
      for (int mi = 0; mi < MI; ++mi)
#pragma unroll
        for (int ni = 0; ni < 4; ++ni)
          acc[mi][ni] = __builtin_amdgcn_mfma_f32_16x16x32_bf16(af[mi], bfr[ni], acc[mi][ni], 0, 0, 0);
    }
    __syncthreads();
  }

#pragma unroll
  for (int mi = 0; mi < MI; ++mi)
#pragma unroll
    for (int r = 0; r < 4; ++r) {
      int row = bm + wm * (BMT / 2) + mi * 16 + lg * 4 + r;
      if (row < M) {
        int orow = SHIFT ? (row + (row >> 11) + 1) : row;
#pragma unroll
        for (int ni = 0; ni < 4; ++ni) {
          int col = bn + wn * 64 + ni * 16 + l15;
          float t = acc[mi][ni][r];
          if (bias) t += bias[col];
          if (ACT) t = geluf(t);
          if (res) t += bf2f(res[(size_t)orow * ldc + col]);
          C[(size_t)orow * ldc + col] = f2bf(t);
        }
      }
    }
}

// ---- MoE variant 1: hid = gelu(h2[tok] @ w1T[e] + b1[e]), BMT tile ---------
template <int BMT>
__global__ __launch_bounds__(256) void moe_mgemm1_kernel(const ushort_t* __restrict__ h2,
                                                         const ushort_t* __restrict__ w1T,
                                                         const float* __restrict__ b1all,
                                                         const int* __restrict__ list,
                                                         const int* __restrict__ cnt,
                                                         ushort_t* __restrict__ hid) {
  constexpr int MI = BMT / 32;
  __shared__ ushort_t As[BMT * 64];
  __shared__ ushort_t Bs[128 * 64];
  const int e = blockIdx.z;
  const int c0 = cnt[e * 2 + 0], c1 = cnt[e * 2 + 1];
  const ushort_t* Bw = w1T + (size_t)e * Dd * FF;
  const int tid = threadIdx.x;
  const int l = tid & 63, l15 = l & 15, lg = l >> 4;
  const int w = tid >> 6;
  const int wm = w >> 1, wn = w & 1;
  const int bm = blockIdx.x * BMT, bn = blockIdx.y * 128;
  const int srowA = w * (BMT / 4) + (l >> 3);
  const int srowB = w * 32 + (l >> 3);
  const int scc = ((l & 7) ^ (l >> 3)) * 8;

  f32x4 acc[MI][4];
#pragma unroll
  for (int i = 0; i < MI; ++i)
#pragma unroll
    for (int j = 0; j < 4; ++j) acc[i][j] = (f32x4){0.f, 0.f, 0.f, 0.f};

  const ushort_t* agp[MI];
  const ushort_t* bgp[4];
#pragma unroll
  for (int j = 0; j < MI; ++j) {
    int r = bm + srowA + j * 8; if (r > MOE_ROWS - 1) r = MOE_ROWS - 1;
    int tok = list[e * MOE_ROWS + r] & (NTOK - 1);
    int b = tok >> 11, s = tok & (Ss - 1);
    agp[j] = h2 + (size_t)(b * S1 + s + 1) * Dd + scc;
  }
#pragma unroll
  for (int j = 0; j < 4; ++j)
    bgp[j] = Bw + (size_t)(bn + srowB + j * 8) * Dd + scc;

  for (int k0 = 0; k0 < Dd; k0 += 64) {
#pragma unroll
    for (int j = 0; j < MI; ++j)
      glds16(agp[j] + k0, (char*)As + w * (BMT * 32) + j * 1024);
#pragma unroll
    for (int j = 0; j < 4; ++j)
      glds16(bgp[j] + k0, (char*)Bs + w * 4096 + j * 1024);
    __syncthreads();
#pragma unroll
    for (int kc = 0; kc < 2; ++kc) {
      bf16x8 af[MI], bfr[4];
#pragma unroll
      for (int mi = 0; mi < MI; ++mi) {
        int row = wm * (BMT / 2) + mi * 16 + l15;
        af[mi] = *(const bf16x8*)((const char*)As +
                   ((row * 128 + (kc * 32 + lg * 8) * 2) ^ ((row & 7) << 4)));
      }
#pragma unroll
      for (int ni = 0; ni < 4; ++ni) {
        int row = wn * 64 + ni * 16 + l15;
        bfr[ni] = *(const bf16x8*)((const char*)Bs +
                   ((row * 128 + (kc * 32 + lg * 8) * 2) ^ ((row & 7) << 4)));
      }
#pragma unroll
      for (int mi = 0; mi < MI; ++mi)
#pragma unroll
        for (int ni = 0; ni < 4; ++ni)
          acc[mi][ni] = __builtin_amdgcn_mfma_f32_16x16x32_bf16(af[mi], bfr[ni], acc[mi][ni], 0, 0, 0);
    }
    __syncthreads();
  }

#pragma unroll
  for (int mi = 0; mi < MI; ++mi)
#pragma unroll
    for (int rr = 0; rr < 4; ++rr) {
      int row = bm + wm * (BMT / 2) + mi * 16 + lg * 4 + rr;
      bool v2 = (row < MOE_ROWS) && ((row < CAP) ? (row < c0) : ((row - CAP) < c1));
      if (v2) {
#pragma unroll
        for (int ni = 0; ni < 4; ++ni) {
          int col = bn + wn * 64 + ni * 16 + l15;
          hid[((size_t)e * MOE_ROWS + row) * FF + col] =
              f2bf(geluf(acc[mi][ni][rr] + b1all[e * FF + col]));
        }
      }
    }
}

// ---- MoE variant 2: out[tok] += topp * (hid @ w2T[e] + b2[e]), BMT tile ----
template <int BMT>
__global__ __launch_bounds__(256) void moe_mgemm2_kernel(const ushort_t* __restrict__ hid,
                                                         const ushort_t* __restrict__ w2T,
                                                         const float* __restrict__ b2all,
                                                         const int* __restrict__ list,
                                                         const int* __restrict__ cnt,
                                                         const float* __restrict__ topp,
                                                         ushort_t* __restrict__ out) {
  constexpr int MI = BMT / 32;
  __shared__ ushort_t As[BMT * 64];
  __shared__ ushort_t Bs[128 * 64];
  const int e = blockIdx.z;
  const int c0 = cnt[e * 2 + 0], c1 = cnt[e * 2 + 1];
  const ushort_t* Bw = w2T + (size_t)e * FF * Dd;
  const int tid = threadIdx.x;
  const int l = tid & 63, l15 = l & 15, lg = l >> 4;
  const int w = tid >> 6;
  const int wm = w >> 1, wn = w & 1;
  const int bm = blockIdx.x * BMT, bn = blockIdx.y * 128;
  const int srowA = w * (BMT / 4) + (l >> 3);
  const int srowB = w * 32 + (l >> 3);
  const int scc = ((l & 7) ^ (l >> 3)) * 8;

  f32x4 acc[MI][4];
#pragma unroll
  for (int i = 0; i < MI; ++i)
#pragma unroll
    for (int j = 0; j < 4; ++j) acc[i][j] = (f32x4){0.f, 0.f, 0.f, 0.f};

  const ushort_t* agp[MI];
  const ushort_t* bgp[4];
#pragma unroll
  for (int j = 0; j < MI; ++j) {
    int r = bm + srowA + j * 8; if (r > MOE_ROWS - 1) r = MOE_ROWS - 1;
    agp[j] = hid + ((size_t)e * MOE_ROWS + r) * FF + scc;
  }
#pragma unroll
  for (int j = 0; j < 4; ++j)
    bgp[j] = Bw + (size_t)(bn + srowB + j * 8) * FF + scc;

  for (int k0 = 0; k0 < FF; k0 += 64) {
#pragma unroll
    for (int j = 0; j < MI; ++j)
      glds16(agp[j] + k0, (char*)As + w * (BMT * 32) + j * 1024);
#pragma unroll
    for (int j = 0; j < 4; ++j)
      glds16(bgp[j] + k0, (char*)Bs + w * 4096 + j * 1024);
    __syncthreads();
#pragma unroll
    for (int kc = 0; kc < 2; ++kc) {
      bf16x8 af[MI], bfr[4];
#pragma unroll
      for (int mi = 0; mi < MI; ++mi) {
        int row = wm * (BMT / 2) + mi * 16 + l15;
        af[mi] = *(const bf16x8*)((const char*)As +
                   ((row * 128 + (kc * 32 + lg * 8) * 2) ^ ((row & 7) << 4)));
      }
#pragma unroll
      for (int ni = 0; ni < 4; ++ni) {
        int row = wn * 64 + ni * 16 + l15;
        bfr[ni] = *(const bf16x8*)((const char*)Bs +
                   ((row * 128 + (kc * 32 + lg * 8) * 2) ^ ((row & 7) << 4)));
      }
#pragma unroll
      for (int mi = 0; mi < MI; ++mi)
#pragma unroll
        for (int ni = 0; ni < 4; ++ni)
          acc[mi][ni] = __builtin_amdgcn_mfma_f32_16x16x32_bf16(af[mi], bfr[ni], acc[mi][ni], 0, 0, 0);
    }
    __syncthreads();
  }

#pragma unroll
  for (int mi = 0; mi < MI; ++mi)
#pragma unroll
    for (int rr = 0; rr < 4; ++rr) {
      int row = bm + wm * (BMT / 2) + mi * 16 + lg * 4 + rr;
      bool v2 = (row < MOE_ROWS) && ((row < CAP) ? (row < c0) : ((row - CAP) < c1));
      if (v2) {
        int tok = list[e * MOE_ROWS + row];
        int b = tok >> 11, s = tok & (Ss - 1);
        float tp = topp[tok];
#pragma unroll
        for (int ni = 0; ni < 4; ++ni) {
          int col = bn + wn * 64 + ni * 16 + l15;
          size_t oidx = (size_t)(b * S1 + s + 1) * Dd + col;
          out[oidx] = f2bf(bf2f(out[oidx]) + tp * (acc[mi][ni][rr] + b2all[e * Dd + col]));
        }
      }
    }
}

// ---------------- cls rows fill (rows 0 and S1) -----------------------------
__global__ __launch_bounds__(256) void cls_fill_kernel(const float* __restrict__ cls,
                                                       ushort_t* __restrict__ h) {
  int i = threadIdx.x;
  uint_t pk = (uint_t)f2bf(cls[i * 2]) | ((uint_t)f2bf(cls[i * 2 + 1]) << 16);
  *(uint_t*)(h + i * 2) = pk;
  *(uint_t*)(h + (size_t)S1 * Dd + i * 2) = pk;
}

// ---------------- wave-per-row LayerNorm (bf16 in/out, fp32 stats) ----------
template <int EPL>
__global__ __launch_bounds__(256) void ln_wave_kernel(const ushort_t* __restrict__ in,
                                                      const ushort_t* __restrict__ addv,
                                                      const float* __restrict__ g,
                                                      const float* __restrict__ bvec,
                                                      ushort_t* __restrict__ out,
                                                      ushort_t* __restrict__ out2,
                                                      int nrows) {
  constexpr int N = 64 * EPL;
  const int row = blockIdx.x * 4 + (threadIdx.x >> 6);
  const int lane = threadIdx.x & 63;
  if (row >= nrows) return;
  const size_t base = (size_t)row * N + lane * EPL;
  float xf[EPL];
  float s1 = 0.f, s2 = 0.f;
#pragma unroll
  for (int c = 0; c < EPL / 8; ++c) {
    bf16x8 x8 = *(const bf16x8*)(in + base + c * 8);
#pragma unroll
    for (int j = 0; j < 8; ++j) {
      float v = bf2f((ushort_t)x8[j]);
      xf[c * 8 + j] = v;
      s1 += v; s2 += v * v;
    }
  }
  s1 = wsum(s1); s2 = wsum(s2);
  float mean = s1 * (1.0f / N);
  float var = s2 * (1.0f / N) - mean * mean;
  float rstd = rsqrtf(var + 1e-5f);
#pragma unroll
  for (int c = 0; c < EPL / 8; ++c) {
    bf16x8 a8;
    if (addv) a8 = *(const bf16x8*)(addv + base + c * 8);
    bf16x8 o8;
#pragma unroll
    for (int j = 0; j < 8; ++j) {
      int col = lane * EPL + c * 8 + j;
      float v = (xf[c * 8 + j] - mean) * rstd * g[col] + bvec[col];
      if (addv) v += bf2f((ushort_t)a8[j]);
      o8[j] = (short)f2bf(v);
    }
    *(bf16x8*)(out + base + c * 8) = o8;
    if (out2) *(bf16x8*)(out2 + base + c * 8) = o8;
  }
}

// ---------------- fused double-LN: out = LN2(LN1(in)+addv) ------------------
__global__ __launch_bounds__(256) void ln2_wave_kernel(const ushort_t* __restrict__ in,
                                                       const ushort_t* __restrict__ addv,
                                                       const float* __restrict__ g1,
                                                       const float* __restrict__ b1,
                                                       const float* __restrict__ g2,
                                                       const float* __restrict__ b2,
                                                       ushort_t* __restrict__ out,
                                                       ushort_t* __restrict__ out2,
                                                       int nrows) {
  constexpr int N = 512;
  const int row = blockIdx.x * 4 + (threadIdx.x >> 6);
  const int lane = threadIdx.x & 63;
  if (row >= nrows) return;
  const size_t base = (size_t)row * N + lane * 8;
  bf16x8 x8 = *(const bf16x8*)(in + base);
  bf16x8 a8 = *(const bf16x8*)(addv + base);
  float xf[8];
  float s1 = 0.f, s2 = 0.f;
#pragma unroll
  for (int j = 0; j < 8; ++j) {
    float v = bf2f((ushort_t)x8[j]);
    xf[j] = v; s1 += v; s2 += v * v;
  }
  s1 = wsum(s1); s2 = wsum(s2);
  float mean = s1 * (1.0f / N);
  float rstd = rsqrtf(s2 * (1.0f / N) - mean * mean + 1e-5f);
  float vf[8];
  float t1 = 0.f, t2 = 0.f;
#pragma unroll
  for (int j = 0; j < 8; ++j) {
    int col = lane * 8 + j;
    float v = (xf[j] - mean) * rstd * g1[col] + b1[col] + bf2f((ushort_t)a8[j]);
    vf[j] = v; t1 += v; t2 += v * v;
  }
  t1 = wsum(t1); t2 = wsum(t2);
  float mean2 = t1 * (1.0f / N);
  float rstd2 = rsqrtf(t2 * (1.0f / N) - mean2 * mean2 + 1e-5f);
  bf16x8 o8;
#pragma unroll
  for (int j = 0; j < 8; ++j) {
    int col = lane * 8 + j;
    o8[j] = (short)f2bf((vf[j] - mean2) * rstd2 * g2[col] + b2[col]);
  }
  *(bf16x8*)(out + base) = o8;
  if (out2) *(bf16x8*)(out2 + base) = o8;
}

// ---------------- MFMA bf16 flash attention -------------------------------
// swapped-QK (lane-local q row), defer-max, 128-key iterations.
// K: double-buffered glds16 staging (prefetch next iter under compute).
// V: coalesced row loads into regs one iter ahead; transposed b16 writes into
//    stride-272 padded Vt with XOR ((d>>3)&7)<<4 (bank-conflict-free both sides).
__global__ __launch_bounds__(256) void attn_mfma_kernel(const ushort_t* __restrict__ qkv,
                                                        ushort_t* __restrict__ o) {
  __shared__ ushort_t Ksh[2][128 * 64];   // [buf][k][d], rows 128B, swz (r&7)<<4
  __shared__ ushort_t Vt[64 * 136];       // [d][k], rows 272B, swz ((d>>3)&7)<<4
  const int tid = threadIdx.x;
  const int w = tid >> 6, l = tid & 63;
  const int l15 = l & 15, lg = l >> 4;
  const int hh = blockIdx.y, b = blockIdx.z;
  const int qblk = blockIdx.x * 64;
  const size_t rbase = (size_t)b * S1 * 1536;
  const float CEXP = 0.125f * 1.4426950408889634f;

  bf16x8 aq[2];
  {
    int qr = qblk + w * 16 + l15;
    const ushort_t* qp = qkv + rbase + (size_t)qr * 1536 + hh * 64;
#pragma unroll
    for (int dc = 0; dc < 2; ++dc)
      aq[dc] = (qr < S1) ? *(const bf16x8*)(qp + dc * 32 + lg * 8)
                         : (bf16x8){0, 0, 0, 0, 0, 0, 0, 0};
  }

  f32x4 ovac[4];
#pragma unroll
  for (int dt = 0; dt < 4; ++dt) ovac[dt] = (f32x4){0.f, 0.f, 0.f, 0.f};
  float m_r = -1e30f, l_r = 0.f;

  const int kcc = ((l & 7) ^ (l >> 3)) * 8;  // K glds16 pre-swizzled chunk
  const int rloc = w * 32 + (l >> 3);        // local row base (K and V)
  const int vd0 = (l & 7) * 8;               // V load d-chunk

  bf16x8 vreg[4];
  // ---- prologue: stage iter 0 ----
  {
#pragma unroll
    for (int p = 0; p < 4; ++p) {
      int key = rloc + p * 8;                // < 128 < S1, no clamp needed
      glds16(qkv + rbase + (size_t)key * 1536 + 512 + hh * 64 + kcc,
             (char*)Ksh[0] + w * 4096 + p * 1024);
      vreg[p] = *(const bf16x8*)(qkv + rbase + (size_t)key * 1536 + 1024 + hh * 64 + vd0);
    }
#pragma unroll
    for (int p = 0; p < 4; ++p) {
      int lk = rloc + p * 8;
#pragma unroll
      for (int j = 0; j < 8; ++j) {
        int d = vd0 + j;
        *(ushort_t*)((char*)Vt + (((d * 272 + lk * 2)) ^ (((d >> 3) & 7) << 4))) =
            (ushort_t)vreg[p][j];
      }
    }
    __syncthreads();
  }

  for (int it = 0; it < 17; ++it) {
    const int cur = it & 1;
    if (it < 16) {   // prefetch next iter: K -> Ksh[cur^1], V -> regs
      int nb = (it + 1) * 128 + rloc;
#pragma unroll
      for (int p = 0; p < 4; ++p) {
        int key = nb + p * 8;
        if (key > S1 - 1) key = S1 - 1;
        glds16(qkv + rbase + (size_t)key * 1536 + 512 + hh * 64 + kcc,
               (char*)Ksh[cur ^ 1] + w * 4096 + p * 1024);
        vreg[p] = *(const bf16x8*)(qkv + rbase + (size_t)key * 1536 + 1024 + hh * 64 + vd0);
      }
    }

    // ---- S^T = K·Q^T (8 k-tiles) ----
    f32x4 s[8];
    __builtin_amdgcn_s_setprio(1);
#pragma unroll
    for (int kt = 0; kt < 8; ++kt) {
      f32x4 acc = (f32x4){0.f, 0.f, 0.f, 0.f};
      const int krow = kt * 16 + l15;
      const int rswz = (krow & 7) << 4;
#pragma unroll
      for (int dc = 0; dc < 2; ++dc) {
        bf16x8 kb = *(const bf16x8*)((const char*)Ksh[cur] +
                     (((krow * 64 + dc * 32 + lg * 8) * 2) ^ rswz));
        acc = __builtin_amdgcn_mfma_f32_16x16x32_bf16(kb, aq[dc], acc, 0, 0, 0);
      }
      s[kt] = acc;
    }
    __builtin_amdgcn_s_setprio(0);
    if (it == 16) {
#pragma unroll
      for (int kt = 0; kt < 8; ++kt)
#pragma unroll
        for (int r = 0; r < 4; ++r)
          if (2048 + kt * 16 + lg * 4 + r >= S1) s[kt][r] = -1e30f;
    }

    // ---- online softmax (lane-local q row) ----
    f32x4 m4 = s[0];
#pragma unroll
    for (int kt = 1; kt < 8; ++kt)
#pragma unroll
      for (int r = 0; r < 4; ++r) m4[r] = fmaxf(m4[r], s[kt][r]);
    float mx = fmaxf(fmaxf(m4[0], m4[1]), fmaxf(m4[2], m4[3]));
    mx = fmaxf(mx, __shfl_xor(mx, 16));
    mx = fmaxf(mx, __shfl_xor(mx, 32));
    if (!__all(mx <= m_r + 8.0f)) {                  // defer-max (T13)
      float mn = fmaxf(m_r, mx);
      float fac = __builtin_amdgcn_exp2f((m_r - mn) * CEXP);
      m_r = mn;
      float facq[4];
#pragma unroll
      for (int r = 0; r < 4; ++r) facq[r] = __shfl(fac, lg * 4 + r);
#pragma unroll
      for (int dt = 0; dt < 4; ++dt)
#pragma unroll
        for (int r = 0; r < 4; ++r) ovac[dt][r] *= facq[r];
      l_r *= fac;
    }
    float mc = m_r * CEXP;
    float rs = 0.f;
#pragma unroll
    for (int kt = 0; kt < 8; ++kt)
#pragma unroll
      for (int r = 0; r < 4; ++r) {
        float pv = __builtin_amdgcn_exp2f(s[kt][r] * CEXP - mc);
        s[kt][r] = pv;
        rs += pv;
      }
    rs += __shfl_xor(rs, 16);
    rs += __shfl_xor(rs, 32);
    l_r += rs;

    // ---- pack P to bf16 pairs ----
    uint_t pk[8][2];
#pragma unroll
    for (int kt = 0; kt < 8; ++kt) {
      pk[kt][0] = (uint_t)f2bf(s[kt][0]) | ((uint_t)f2bf(s[kt][1]) << 16);
      pk[kt][1] = (uint_t)f2bf(s[kt][2]) | ((uint_t)f2bf(s[kt][3]) << 16);
    }

    // ---- in-register transpose: P -> PV A-frags ----
    bf16x8 pa[4];
#pragma unroll
    for (int kh = 0; kh < 4; ++kh) {
      union { uint_t u[4]; bf16x8 v; } cu;
#pragma unroll
      for (int wd = 0; wd < 4; ++wd) {
        int src = (((2 * lg + (wd >> 1)) & 3) << 4) + l15;
        uint_t c0 = (uint_t)__shfl((int)pk[kh * 2 + 0][wd & 1], src);
        uint_t c1 = (uint_t)__shfl((int)pk[kh * 2 + 1][wd & 1], src);
        cu.u[wd] = (lg & 2) ? c1 : c0;
      }
      pa[kh] = cu.v;
    }

    // ---- O += P @ V ----
    __builtin_amdgcn_s_setprio(1);
#pragma unroll
    for (int kh = 0; kh < 4; ++kh)
#pragma unroll
      for (int dt = 0; dt < 4; ++dt) {
        const int vrow = dt * 16 + l15;
        bf16x8 vb = *(const bf16x8*)((const char*)Vt +
                      (((vrow * 272 + (kh * 32 + lg * 8) * 2)) ^ (((vrow >> 3) & 7) << 4)));
        ovac[dt] = __builtin_amdgcn_mfma_f32_16x16x32_bf16(pa[kh], vb, ovac[dt], 0, 0, 0);
      }
    __builtin_amdgcn_s_setprio(0);
    __syncthreads();            // Vt readers done; drains prefetched loads

    if (it < 16) {              // write prefetched V into Vt
#pragma unroll
      for (int p = 0; p < 4; ++p) {
        int lk = rloc + p * 8;
#pragma unroll
        for (int j = 0; j < 8; ++j) {
          int d = vd0 + j;
          *(ushort_t*)((char*)Vt + (((d * 272 + lk * 2)) ^ (((d >> 3) & 7) << 4))) =
              (ushort_t)vreg[p][j];
        }
      }
      __syncthreads();          // Vt writes visible for next compute
    }
  }

  float invq[4];
#pragma unroll
  for (int r = 0; r < 4; ++r) invq[r] = 1.0f / __shfl(l_r, lg * 4 + r);
#pragma unroll
  for (int r = 0; r < 4; ++r) {
    int qq = qblk + w * 16 + lg * 4 + r;
    if (qq < S1) {
      ushort_t* orow = o + (size_t)(b * S1 + qq) * Dd + hh * 64;
#pragma unroll
      for (int dt = 0; dt < 4; ++dt) orow[dt * 16 + l15] = f2bf(ovac[dt][r] * invq[r]);
    }
  }
}

// ---------------- gate softmax + top1 routing info (bf16 h) -----------------
__global__ __launch_bounds__(256) void gate_kernel(const ushort_t* __restrict__ h2,
                                                   const float* __restrict__ gw,
                                                   float* __restrict__ gate_out,
                                                   float* __restrict__ topp,
                                                   int* __restrict__ idx) {
  int t = blockIdx.x * 4 + (threadIdx.x >> 6);
  int lane = threadIdx.x & 63;
  if (t >= NTOK) return;
  int b = t >> 11, s = t & (Ss - 1);
  const ushort_t* hr = h2 + (size_t)(b * S1 + s + 1) * Dd;
  bf16x8 h8 = *(const bf16x8*)(hr + lane * 8);
  float acc[6] = {};
#pragma unroll
  for (int j = 0; j < 8; ++j) {
    int d = lane * 8 + j;
    float xv = bf2f((ushort_t)h8[j]);
    const float* g = gw + (size_t)d * Ee;
#pragma unroll
    for (int e = 0; e < 6; ++e) acc[e] += xv * g[e];
  }
#pragma unroll
  for (int e = 0; e < 6; ++e) acc[e] = wsum(acc[e]);
  if (lane == 0) {
    float mx = acc[0];
#pragma unroll
    for (int e = 1; e < 6; ++e) mx = fmaxf(mx, acc[e]);
    float ex[6], sum = 0.f;
#pragma unroll
    for (int e = 0; e < 6; ++e) { ex[e] = __expf(acc[e] - mx); sum += ex[e]; }
    float invs = 1.0f / sum;
    int best = 0; float bp = ex[0];
#pragma unroll
    for (int e = 1; e < 6; ++e) { if (ex[e] > bp) { bp = ex[e]; best = e; } }
#pragma unroll
    for (int e = 0; e < 6; ++e) gate_out[(size_t)t * Ee + e] = ex[e] * invs;
    topp[t] = bp * invs;
    idx[t] = best;
  }
}

// ---------------- capacity-limited top-1 router (parallel scan) -------------
__global__ __launch_bounds__(256) void route_kernel(const int* __restrict__ idx,
                                                    int* __restrict__ list,
                                                    int* __restrict__ cnt) {
  __shared__ int cnts[256];
  __shared__ int tot;
  const int e = blockIdx.x, b = blockIdx.y;
  const int tid = threadIdx.x;
  const int s0 = tid * 8;
  int loc[8];
  int c = 0;
#pragma unroll
  for (int j = 0; j < 8; ++j) {
    int t = b * Ss + s0 + j;
    if (idx[t] == e) loc[c++] = t;
  }
  cnts[tid] = c;
  __syncthreads();
  if (tid == 0) {
    int run = 0;
    for (int i = 0; i < 256; ++i) { int v = cnts[i]; cnts[i] = run; run += v; }
    tot = run;
  }
  __syncthreads();
  int base = cnts[tid];
  for (int j = 0; j < c; ++j) {
    int pos = base + j;
    if (pos < CAP) list[e * MOE_ROWS + b * CAP + pos] = loc[j];
  }
  if (tid == 0) cnt[e * Bb + b] = (tot < CAP) ? tot : CAP;
}

// ---------------- cls-token sub-LN FFN, split-K parallel --------------------
__global__ __launch_bounds__(256) void cls_ffn1_kernel(const ushort_t* __restrict__ h2,
                                                       const float* __restrict__ w1,
                                                       const float* __restrict__ b1,
                                                       float* __restrict__ chid) {
  __shared__ float hrow[Dd];
  __shared__ float red[8][32];
  const int b = blockIdx.y, tid = threadIdx.x;
  const int cl = tid & 31, kp = tid >> 5;
  const int col = blockIdx.x * 32 + cl;
  const ushort_t* hr = h2 + (size_t)(b * S1) * Dd;
  hrow[tid] = bf2f(hr[tid]);
  hrow[tid + 256] = bf2f(hr[tid + 256]);
  __syncthreads();
  float acc = 0.f;
#pragma unroll 8
  for (int j = 0; j < 64; ++j) {
    int d = kp * 64 + j;
    acc += hrow[d] * w1[(size_t)d * FF + col];
  }
  red[kp][cl] = acc;
  __syncthreads();
  if (kp == 0) {
    float s = b1[col];
#pragma unroll
    for (int i = 0; i < 8; ++i) s += red[i][cl];
    chid[b * FF + col] = geluf(s);
  }
}

__global__ __launch_bounds__(256) void cls_ln_kernel(const float* __restrict__ chid,
                                                     const float* __restrict__ lg,
                                                     const float* __restrict__ lb,
                                                     float* __restrict__ chln) {
  __shared__ float red[8];
  const int b = blockIdx.x, tid = threadIdx.x;
  const float* hr = chid + b * FF;
  float hv[8];
  float s1 = 0.f, s2 = 0.f;
#pragma unroll
  for (int j = 0; j < 8; ++j) {
    hv[j] = hr[tid + j * 256];
    s1 += hv[j]; s2 += hv[j] * hv[j];
  }
  s1 = bsum(s1, red);
  s2 = bsum(s2, red);
  float mean = s1 * (1.0f / FF);
  float rstd = rsqrtf(s2 * (1.0f / FF) - mean * mean + 1e-5f);
#pragma unroll
  for (int j = 0; j < 8; ++j) {
    int k = tid + j * 256;
    chln[b * FF + k] = (hv[j] - mean) * rstd * lg[k] + lb[k];
  }
}

__global__ __launch_bounds__(256) void cls_ffn2_kernel(const float* __restrict__ chln,
                                                       const float* __restrict__ w2,
                                                       const float* __restrict__ b2,
                                                       ushort_t* __restrict__ outbuf) {
  __shared__ float red[8][32];
  const int b = blockIdx.y, tid = threadIdx.x;
  const int cl = tid & 31, kp = tid >> 5;
  const int col = blockIdx.x * 32 + cl;
  const float* hr = chln + b * FF;
  float acc = 0.f;
#pragma unroll 8
  for (int j = 0; j < 256; ++j) {
    int k = kp * 256 + j;
    acc += hr[k] * w2[(size_t)k * Dd + col];
  }
  red[kp][cl] = acc;
  __syncthreads();
  if (kp == 0) {
    float s = b2[col];
#pragma unroll
    for (int i = 0; i < 8; ++i) s += red[i][cl];
    size_t oidx = (size_t)(b * S1) * Dd + col;
    outbuf[oidx] = f2bf(bf2f(outbuf[oidx]) + s);
  }
}

// ---------------- loss ------------------------------------------------------
__global__ __launch_bounds__(256) void loss_part_kernel(const float* __restrict__ gate,
                                                        const int* __restrict__ lbl,
                                                        float* __restrict__ part) {
  __shared__ float red[8];
  int t = blockIdx.x * 256 + threadIdx.x;
  float v = 0.f;
  if (t < NTOK) {
    const float* p = gate + (size_t)t * Ee;
    float sum = p[0] + p[1] + p[2] + p[3];
    float pl = p[lbl[t]];
    v = -logf(pl / sum + 1e-9f);
  }
  v = bsum(v, red);
  if (threadIdx.x == 0) part[blockIdx.x] = v;
}

__global__ void loss_final_kernel(const float* __restrict__ part, float* __restrict__ out) {
  if (threadIdx.x == 0) {
    float s = 0.f;
    for (int i = 0; i < 16; ++i) s += part[i];
    out[NTOK * Ee + Bb * NCc] = s / (float)NTOK;
  }
}

// ---------------- final LN + logits ----------------------------------------
__global__ __launch_bounds__(256) void final_head_kernel(const ushort_t* __restrict__ h,
                                                         const float* __restrict__ g,
                                                         const float* __restrict__ bvec,
                                                         const float* __restrict__ w,
                                                         const float* __restrict__ fb,
                                                         float* __restrict__ out) {
  __shared__ float red[8];
  int b = blockIdx.x, tid = threadIdx.x;
  const ushort_t* hr = h + (size_t)(b * S1) * Dd;
  float x0 = bf2f(hr[tid]), x1 = bf2f(hr[tid + 256]);
  float s1 = bsum(x0 + x1, red);
  float s2 = bsum(x0 * x0 + x1 * x1, red);
  float mean = s1 * (1.0f / Dd);
  float var = s2 * (1.0f / Dd) - mean * mean;
  float rstd = rsqrtf(var + 1e-5f);
  float p0 = (x0 - mean) * rstd * g[tid] + bvec[tid];
  float p1 = (x1 - mean) * rstd * g[tid + 256] + bvec[tid + 256];
  float l0 = p0 * w[tid * 2 + 0] + p1 * w[(tid + 256) * 2 + 0];
  float l1 = p0 * w[tid * 2 + 1] + p1 * w[(tid + 256) * 2 + 1];
  l0 = bsum(l0, red);
  l1 = bsum(l1, red);
  if (tid == 0) {
    out[NTOK * Ee + b * NCc + 0] = l0 + fb[0];
    out[NTOK * Ee + b * NCc + 1] = l1 + fb[1];
  }
}

// ============================================================================
extern "C" void kernel_launch(void* const* d_in, const int* in_sizes, int n_in,
                              void* d_out, int out_size, void* d_ws, size_t ws_size,
                              hipStream_t stream) {
  (void)in_sizes; (void)n_in; (void)out_size; (void)ws_size;
  const float* x       = (const float*)d_in[0];
  const float* protos  = (const float*)d_in[1];
  const float* cls_tok = (const float*)d_in[2];
  const float* fc1_w   = (const float*)d_in[3];
  const float* fc1_b   = (const float*)d_in[4];
  const float* a0_in_w = (const float*)d_in[5];
  const float* a0_in_b = (const float*)d_in[6];
  const float* a0_out_w= (const float*)d_in[7];
  const float* a0_out_b= (const float*)d_in[8];
  const float* n1g0    = (const float*)d_in[9];
  const float* n1b0    = (const float*)d_in[10];
  const float* n2g0    = (const float*)d_in[11];
  const float* n2b0    = (const float*)d_in[12];
  const float* a1_in_w = (const float*)d_in[13];
  const float* a1_in_b = (const float*)d_in[14];
  const float* a1_out_w= (const float*)d_in[15];
  const float* a1_out_b= (const float*)d_in[16];
  const float* n1g1    = (const float*)d_in[17];
  const float* n1b1    = (const float*)d_in[18];
  const float* n2g1    = (const float*)d_in[19];
  const float* n2b1    = (const float*)d_in[20];
  const float* cw1     = (const float*)d_in[21];
  const float* cb1     = (const float*)d_in[22];
  const float* clg     = (const float*)d_in[23];
  const float* clb     = (const float*)d_in[24];
  const float* cw2     = (const float*)d_in[25];
  const float* cb2     = (const float*)d_in[26];
  const float* gate_w  = (const float*)d_in[27];
  const float* ew1     = (const float*)d_in[28];
  const float* eb1     = (const float*)d_in[29];
  const float* ew2     = (const float*)d_in[30];
  const float* eb2     = (const float*)d_in[31];
  const float* fw1     = (const float*)d_in[32];
  const float* fb1     = (const float*)d_in[33];
  const float* flg     = (const float*)d_in[34];
  const float* flb     = (const float*)d_in[35];
  const float* fw2     = (const float*)d_in[36];
  const float* fb2     = (const float*)d_in[37];
  const float* ng      = (const float*)d_in[38];
  const float* nb      = (const float*)d_in[39];
  const float* fc2_w   = (const float*)d_in[40];
  const float* fc2_b   = (const float*)d_in[41];
  float* out = (float*)d_out;

  char* base = (char*)d_ws;
  size_t o = 0;
  auto alloc = [&](size_t bytes) -> void* {
    void* p = base + o;
    o += (bytes + 255) & ~(size_t)255;
    return p;
  };
  ushort_t* UB0  = (ushort_t*)alloc((size_t)RR * Dd * 2);
  ushort_t* UB1  = (ushort_t*)alloc((size_t)RR * Dd * 2);
  ushort_t* UB2  = (ushort_t*)alloc((size_t)RR * Dd * 2);
  ushort_t* BIGU = (ushort_t*)alloc((size_t)RR * FF * 2);
  ushort_t* XB   = (ushort_t*)alloc((size_t)NTOK * DIN * 2);
  ushort_t* WQ0  = (ushort_t*)alloc((size_t)3 * Dd * Dd * 2);
  ushort_t* WO0  = (ushort_t*)alloc((size_t)Dd * Dd * 2);
  ushort_t* WQ1  = (ushort_t*)alloc((size_t)3 * Dd * Dd * 2);
  ushort_t* WO1  = (ushort_t*)alloc((size_t)Dd * Dd * 2);
  ushort_t* WF1T = (ushort_t*)alloc((size_t)Dd * DIN * 2);
  ushort_t* WE1T = (ushort_t*)alloc((size_t)Ee * FF * Dd * 2);
  ushort_t* WE2T = (ushort_t*)alloc((size_t)Ee * Dd * FF * 2);
  ushort_t* WFW1T= (ushort_t*)alloc((size_t)FF * Dd * 2);
  ushort_t* WFW2T= (ushort_t*)alloc((size_t)Dd * FF * 2);
  float* TOPP = (float*)alloc(NTOK * 4);
  float* PART = (float*)alloc(64 * 4);
  float* CHID = (float*)alloc(Bb * FF * 4);
  float* CHLN = (float*)alloc(Bb * FF * 4);
  int* LBL  = (int*)alloc(NTOK * 4);
  int* IDX  = (int*)alloc(NTOK * 4);
  int* LIST = (int*)alloc(Ee * MOE_ROWS * 4);
  int* CNT  = (int*)alloc(Ee * Bb * 4);

  const int ln_grid = (RR + 3) / 4;

  // ---- one-shot conversions (bf16, unified NxK) ----
  cast5_kernel<<<(C5_T + 255) / 256, 256, 0, stream>>>(
      x, XB, a0_in_w, WQ0, a0_out_w, WO0, a1_in_w, WQ1, a1_out_w, WO1);
  tpose_cast_kernel<<<dim3(DIN / 64, Dd / 64, 1), 256, 0, stream>>>(fc1_w, WF1T, DIN, Dd);
  tpose_cast_kernel<<<dim3(Dd / 64, FF / 64, Ee), 256, 0, stream>>>(ew1, WE1T, Dd, FF);
  tpose_cast_kernel<<<dim3(FF / 64, Dd / 64, Ee), 256, 0, stream>>>(ew2, WE2T, FF, Dd);
  tpose_cast_kernel<<<dim3(Dd / 64, FF / 64, 1), 256, 0, stream>>>(fw1, WFW1T, Dd, FF);
  tpose_cast_kernel<<<dim3(FF / 64, Dd / 64, 1), 256, 0, stream>>>(fw2, WFW2T, FF, Dd);

  // 1. labels
  labels_kernel<<<NTOK / 4, 256, 0, stream>>>(x, protos, LBL);
  // 2. fc1 writes straight into shifted h layout (UB0); cls rows filled apart
  mgemm_kernel<false, true, 64><<<dim3(64, 4), 256, 0, stream>>>(
      XB, DIN, WF1T, DIN, fc1_b, nullptr, UB0, Dd, NTOK, Dd, DIN);
  cls_fill_kernel<<<1, 256, 0, stream>>>(cls_tok, UB0);

  // ---- layer 0 attention ----
  mgemm_kernel<false, false, 64><<<dim3(65, 12), 256, 0, stream>>>(
      UB0, Dd, WQ0, Dd, a0_in_b, nullptr, BIGU, 3 * Dd, RR, 3 * Dd, Dd);
  attn_mfma_kernel<<<dim3(33, Hh, Bb), 256, 0, stream>>>(BIGU, UB1);
  mgemm_kernel<false, false, 64><<<dim3(65, 4), 256, 0, stream>>>(
      UB1, Dd, WO0, Dd, a0_out_b, nullptr, UB2, Dd, RR, Dd, Dd);
  // h2 = LN2(LN1(UB0)+UB2) -> UB0 (+UB2 as h_res), fused
  ln2_wave_kernel<<<ln_grid, 256, 0, stream>>>(UB0, UB2, n1g0, n1b0, n2g0, n2b0, UB0, UB2, RR);

  // ---- cls ffn (split-K), gate, route, moe ----
  cls_ffn1_kernel<<<dim3(FF / 32, Bb), 256, 0, stream>>>(UB0, cw1, cb1, CHID);
  cls_ln_kernel<<<Bb, 256, 0, stream>>>(CHID, clg, clb, CHLN);
  cls_ffn2_kernel<<<dim3(Dd / 32, Bb), 256, 0, stream>>>(CHLN, cw2, cb2, UB2);
  gate_kernel<<<NTOK / 4, 256, 0, stream>>>(UB0, gate_w, out, TOPP, IDX);
  route_kernel<<<dim3(Ee, Bb), 256, 0, stream>>>(IDX, LIST, CNT);
  moe_mgemm1_kernel<64><<<dim3(11, 16, Ee), 256, 0, stream>>>(UB0, WE1T, eb1, LIST, CNT, BIGU);
  moe_mgemm2_kernel<64><<<dim3(11, 4, Ee), 256, 0, stream>>>(BIGU, WE2T, eb2, LIST, CNT, TOPP, UB2);
  loss_part_kernel<<<16, 256, 0, stream>>>(out, LBL, PART);
  loss_final_kernel<<<1, 64, 0, stream>>>(PART, out);

  // ---- layer 1 attention ----
  mgemm_kernel<false, false, 64><<<dim3(65, 12), 256, 0, stream>>>(
      UB2, Dd, WQ1, Dd, a1_in_b, nullptr, BIGU, 3 * Dd, RR, 3 * Dd, Dd);
  attn_mfma_kernel<<<dim3(33, Hh, Bb), 256, 0, stream>>>(BIGU, UB1);
  mgemm_kernel<false, false, 64><<<dim3(65, 4), 256, 0, stream>>>(
      UB1, Dd, WO1, Dd, a1_out_b, nullptr, UB0, Dd, RR, Dd, Dd);
  // h = LN2(LN1(UB2)+UB0) -> UB2, fused
  ln2_wave_kernel<<<ln_grid, 256, 0, stream>>>(UB2, UB0, n1g1, n1b1, n2g1, n2b1, UB2, nullptr, RR);

  // ---- layer 1 FFN (sub-LN) with residual ----
  mgemm_kernel<true, false, 64><<<dim3(65, 16), 256, 0, stream>>>(
      UB2, Dd, WFW1T, Dd, fb1, nullptr, BIGU, FF, RR, FF, Dd);
  ln_wave_kernel<32><<<ln_grid, 256, 0, stream>>>(BIGU, nullptr, flg, flb, BIGU, nullptr, RR);
  mgemm_kernel<false, false, 64><<<dim3(65, 4), 256, 0, stream>>>(
      BIGU, FF, WFW2T, FF, fb2, UB2, UB0, Dd, RR, Dd, FF);

  // ---- head ----
  final_head_kernel<<<Bb, 256, 0, stream>>>(UB0, ng, nb, fc2_w, fc2_b, out);
}

// Round 13
// 471.198 us; speedup vs baseline: 1.0776x; 1.0776x over previous
//
#include <hip/hip_runtime.h>
#include <cmath>

#define DEVINL __device__ __forceinline__

typedef unsigned short ushort_t;
typedef unsigned int uint_t;

constexpr int Bb   = 2;
constexpr int Ss   = 2048;
constexpr int S1   = 2049;
constexpr int DIN  = 1024;
constexpr int Dd   = 512;
constexpr int Hh   = 8;
constexpr int FF   = 2048;
constexpr int Ee   = 6;
constexpr int NCc  = 2;
constexpr int CAP  = 341;
constexpr int NTOK = Bb * Ss;     // 4096
constexpr int RR   = Bb * S1;     // 4098
constexpr int MOE_ROWS = Bb * CAP; // 682

typedef __attribute__((ext_vector_type(4))) float f32x4;
typedef __attribute__((ext_vector_type(8))) short bf16x8;

DEVINL float geluf(float x) { return 0.5f * x * (1.0f + erff(x * 0.7071067811865476f)); }

DEVINL ushort_t f2bf(float f) {
  uint_t u = __float_as_uint(f);
  u += 0x7FFFu + ((u >> 16) & 1u);
  return (ushort_t)(u >> 16);
}
DEVINL float bf2f(ushort_t u) { return __uint_as_float((uint_t)u << 16); }

// async global->LDS, 16B per lane; LDS dest = wave-uniform base + lane*16,
// global src per-lane (pre-swizzled).  [m97/m104/m173 pattern]
DEVINL void glds16(const ushort_t* g, void* lds) {
  __builtin_amdgcn_global_load_lds(
      (const __attribute__((address_space(1))) void*)g,
      (__attribute__((address_space(3))) void*)lds, 16, 0, 0);
}

DEVINL float wsum(float v) {
#pragma unroll
  for (int off = 32; off; off >>= 1) v += __shfl_xor(v, off);
  return v;
}
DEVINL float bsum(float v, float* red) {
  v = wsum(v);
  int w = threadIdx.x >> 6;
  if ((threadIdx.x & 63) == 0) red[w] = v;
  __syncthreads();
  float r = red[0] + red[1] + red[2] + red[3];
  __syncthreads();
  return r;
}

// ---------------- batched fp32->bf16 cast: x + 4 attn weights ---------------
constexpr int C5_N0 = NTOK * DIN / 8;          // 524288
constexpr int C5_N1 = 3 * Dd * Dd / 8;         // 98304
constexpr int C5_N2 = Dd * Dd / 8;             // 32768
constexpr int C5_T  = C5_N0 + 2 * C5_N1 + 2 * C5_N2;  // 786432
__global__ __launch_bounds__(256) void cast5_kernel(const float* __restrict__ s0, ushort_t* __restrict__ d0,
                                                    const float* __restrict__ s1, ushort_t* __restrict__ d1,
                                                    const float* __restrict__ s2, ushort_t* __restrict__ d2,
                                                    const float* __restrict__ s3, ushort_t* __restrict__ d3,
                                                    const float* __restrict__ s4, ushort_t* __restrict__ d4) {
  int i = blockIdx.x * 256 + threadIdx.x;
  if (i >= C5_T) return;
  const float* src; ushort_t* dst; int off;
  if (i < C5_N0) { src = s0; dst = d0; off = i; }
  else if (i < C5_N0 + C5_N1) { src = s1; dst = d1; off = i - C5_N0; }
  else if (i < C5_N0 + C5_N1 + C5_N2) { src = s2; dst = d2; off = i - C5_N0 - C5_N1; }
  else if (i < C5_N0 + 2 * C5_N1 + C5_N2) { src = s3; dst = d3; off = i - C5_N0 - C5_N1 - C5_N2; }
  else { src = s4; dst = d4; off = i - C5_N0 - 2 * C5_N1 - C5_N2; }
  float4 a = *(const float4*)(src + (size_t)off * 8);
  float4 b = *(const float4*)(src + (size_t)off * 8 + 4);
  bf16x8 v;
  v[0] = (short)f2bf(a.x); v[1] = (short)f2bf(a.y);
  v[2] = (short)f2bf(a.z); v[3] = (short)f2bf(a.w);
  v[4] = (short)f2bf(b.x); v[5] = (short)f2bf(b.y);
  v[6] = (short)f2bf(b.z); v[7] = (short)f2bf(b.w);
  *(bf16x8*)(dst + (size_t)off * 8) = v;
}

// KxN fp32 -> NxK bf16 (batched over z)
__global__ __launch_bounds__(256) void tpose_cast_kernel(const float* __restrict__ in,
                                                         ushort_t* __restrict__ outp,
                                                         int K, int N) {
  __shared__ float t[64][65];
  const int z = blockIdx.z;
  const float* src = in + (size_t)z * K * N;
  ushort_t* dst = outp + (size_t)z * K * N;
  const int k0 = blockIdx.x * 64, n0 = blockIdx.y * 64;
  const int tx = threadIdx.x & 15, ty = threadIdx.x >> 4;
#pragma unroll
  for (int p = 0; p < 4; ++p) {
    int k = ty + p * 16;
    float4 v = *(const float4*)(src + (size_t)(k0 + k) * N + n0 + tx * 4);
    t[k][tx * 4 + 0] = v.x; t[k][tx * 4 + 1] = v.y;
    t[k][tx * 4 + 2] = v.z; t[k][tx * 4 + 3] = v.w;
  }
  __syncthreads();
#pragma unroll
  for (int p = 0; p < 4; ++p) {
    int n = ty + p * 16;
    uint_t lo = (uint_t)f2bf(t[tx * 4 + 0][n]) | ((uint_t)f2bf(t[tx * 4 + 1][n]) << 16);
    uint_t hi = (uint_t)f2bf(t[tx * 4 + 2][n]) | ((uint_t)f2bf(t[tx * 4 + 3][n]) << 16);
    *(uint2*)(dst + (size_t)(n0 + n) * K + k0 + tx * 4) = make_uint2(lo, hi);
  }
}

// ---------------- labels: cosine-sim argmax over 4 protos -------------------
__global__ __launch_bounds__(256) void labels_kernel(const float* __restrict__ x,
                                                     const float* __restrict__ protos,
                                                     int* __restrict__ lbl) {
  int t = blockIdx.x * 4 + (threadIdx.x >> 6);
  int lane = threadIdx.x & 63;
  if (t >= NTOK) return;
  const float* xr = x + (size_t)t * DIN;
  float xv[16];
  float ss = 0.f;
#pragma unroll
  for (int i = 0; i < 16; ++i) { xv[i] = xr[lane + 64 * i]; ss += xv[i] * xv[i]; }
  ss = wsum(ss);
  float nx = sqrtf(ss) + 1e-8f;
  float best = -2e30f; int bi = 0;
  for (int p = 0; p < 4; ++p) {
    const float* pr = protos + (size_t)p * DIN;
    float dp = 0.f, pp = 0.f;
#pragma unroll
    for (int i = 0; i < 16; ++i) { float v = pr[lane + 64 * i]; dp += v * xv[i]; pp += v * v; }
    dp = wsum(dp); pp = wsum(pp);
    float sim = dp / (nx * (sqrtf(pp) + 1e-8f));
    if (sim > best) { best = sim; bi = p; }
  }
  if (lane == 0) lbl[t] = bi;
}

// ================= bf16 MFMA GEMM, global_load_lds staging ==================
// C(MxN) bf16 = act(A @ B^T + bias) [+ res].  A bf16 MxK row-major,
// B bf16 NxK row-major.  SHIFT: C row remap row -> row + row/2048 + 1.
// BMT in {64,128}: tile BMTx128x64, 4 waves 2x2, wave tile (BMT/2)x64.
template <bool ACT, bool SHIFT, int BMT>
__global__ __launch_bounds__(256) void mgemm_kernel(const ushort_t* __restrict__ A, int lda,
                                                    const ushort_t* __restrict__ Bw, int ldb,
                                                    const float* __restrict__ bias,
                                                    const ushort_t* __restrict__ res,
                                                    ushort_t* __restrict__ C, int ldc,
                                                    int M, int N, int K) {
  constexpr int MI = BMT / 32;              // A frags per wave (2 or 4)
  __shared__ ushort_t As[BMT * 64];
  __shared__ ushort_t Bs[128 * 64];
  const int tid = threadIdx.x;
  const int l = tid & 63, l15 = l & 15, lg = l >> 4;
  const int w = tid >> 6;
  const int wm = w >> 1, wn = w & 1;
  const int bm = blockIdx.x * BMT, bn = blockIdx.y * 128;
  const int srowA = w * (BMT / 4) + (l >> 3);
  const int srowB = w * 32 + (l >> 3);
  const int scc = ((l & 7) ^ (l >> 3)) * 8;

  f32x4 acc[MI][4];
#pragma unroll
  for (int i = 0; i < MI; ++i)
#pragma unroll
    for (int j = 0; j < 4; ++j) acc[i][j] = (f32x4){0.f, 0.f, 0.f, 0.f};

  const ushort_t* agp[MI];
  const ushort_t* bgp[4];
#pragma unroll
  for (int j = 0; j < MI; ++j) {
    int ar = bm + srowA + j * 8; if (ar > M - 1) ar = M - 1;
    agp[j] = A + (size_t)ar * lda + scc;
  }
#pragma unroll
  for (int j = 0; j < 4; ++j)
    bgp[j] = Bw + (size_t)(bn + srowB + j * 8) * ldb + scc;

  for (int k0 = 0; k0 < K; k0 += 64) {
#pragma unroll
    for (int j = 0; j < MI; ++j)
      glds16(agp[j] + k0, (char*)As + w * (BMT * 32) + j * 1024);
#pragma unroll
    for (int j = 0; j < 4; ++j)
      glds16(bgp[j] + k0, (char*)Bs + w * 4096 + j * 1024);
    __syncthreads();
#pragma unroll
    for (int kc = 0; kc < 2; ++kc) {
      bf16x8 af[MI], bfr[4];
#pragma unroll
      for (int mi = 0; mi < MI; ++mi) {
        int row = wm * (BMT / 2) + mi * 16 + l15;
        af[mi] = *(const bf16x8*)((const char*)As +
                   ((row * 128 + (kc * 32 + lg * 8) * 2) ^ ((row & 7) << 4)));
      }
#pragma unroll
      for (int ni = 0; ni < 4; ++ni) {
        int row = wn * 64 + ni * 16 + l15;
        bfr[ni] = *(const bf16x8*)((const char*)Bs +
                   ((row * 128 + (kc * 32 + lg * 8) * 2) ^ ((row & 7) << 4)));
      }
#pragma unroll
      for (int mi = 0; mi < MI; ++mi)
#pragma unroll
        for (int ni = 0; ni < 4; ++ni)
          acc[mi][ni] = __builtin_amdgcn_mfma_f32_16x16x32_bf16(af[mi], bfr[ni], acc[mi][ni], 0, 0, 0);
    }
    __syncthreads();
  }

#pragma unroll
  for (int mi = 0; mi < MI; ++mi)
#pragma unroll
    for (int r = 0; r < 4; ++r) {
      int row = bm + wm * (BMT / 2) + mi * 16 + lg * 4 + r;
      if (row < M) {
        int orow = SHIFT ? (row + (row >> 11) + 1) : row;
#pragma unroll
        for (int ni = 0; ni < 4; ++ni) {
          int col = bn + wn * 64 + ni * 16 + l15;
          float t = acc[mi][ni][r];
          if (bias) t += bias[col];
          if (ACT) t = geluf(t);
          if (res) t += bf2f(res[(size_t)orow * ldc + col]);
          C[(size_t)orow * ldc + col] = f2bf(t);
        }
      }
    }
}

// ---- MoE variant 1: hid = gelu(h2[tok] @ w1T[e] + b1[e]), BMT tile ---------
template <int BMT>
__global__ __launch_bounds__(256) void moe_mgemm1_kernel(const ushort_t* __restrict__ h2,
                                                         const ushort_t* __restrict__ w1T,
                                                         const float* __restrict__ b1all,
                                                         const int* __restrict__ list,
                                                         const int* __restrict__ cnt,
                                                         ushort_t* __restrict__ hid) {
  constexpr int MI = BMT / 32;
  __shared__ ushort_t As[BMT * 64];
  __shared__ ushort_t Bs[128 * 64];
  const int e = blockIdx.z;
  const int c0 = cnt[e * 2 + 0], c1 = cnt[e * 2 + 1];
  const ushort_t* Bw = w1T + (size_t)e * Dd * FF;
  const int tid = threadIdx.x;
  const int l = tid & 63, l15 = l & 15, lg = l >> 4;
  const int w = tid >> 6;
  const int wm = w >> 1, wn = w & 1;
  const int bm = blockIdx.x * BMT, bn = blockIdx.y * 128;
  const int srowA = w * (BMT / 4) + (l >> 3);
  const int srowB = w * 32 + (l >> 3);
  const int scc = ((l & 7) ^ (l >> 3)) * 8;

  f32x4 acc[MI][4];
#pragma unroll
  for (int i = 0; i < MI; ++i)
#pragma unroll
    for (int j = 0; j < 4; ++j) acc[i][j] = (f32x4){0.f, 0.f, 0.f, 0.f};

  const ushort_t* agp[MI];
  const ushort_t* bgp[4];
#pragma unroll
  for (int j = 0; j < MI; ++j) {
    int r = bm + srowA + j * 8; if (r > MOE_ROWS - 1) r = MOE_ROWS - 1;
    int tok = list[e * MOE_ROWS + r] & (NTOK - 1);
    int b = tok >> 11, s = tok & (Ss - 1);
    agp[j] = h2 + (size_t)(b * S1 + s + 1) * Dd + scc;
  }
#pragma unroll
  for (int j = 0; j < 4; ++j)
    bgp[j] = Bw + (size_t)(bn + srowB + j * 8) * Dd + scc;

  for (int k0 = 0; k0 < Dd; k0 += 64) {
#pragma unroll
    for (int j = 0; j < MI; ++j)
      glds16(agp[j] + k0, (char*)As + w * (BMT * 32) + j * 1024);
#pragma unroll
    for (int j = 0; j < 4; ++j)
      glds16(bgp[j] + k0, (char*)Bs + w * 4096 + j * 1024);
    __syncthreads();
#pragma unroll
    for (int kc = 0; kc < 2; ++kc) {
      bf16x8 af[MI], bfr[4];
#pragma unroll
      for (int mi = 0; mi < MI; ++mi) {
        int row = wm * (BMT / 2) + mi * 16 + l15;
        af[mi] = *(const bf16x8*)((const char*)As +
                   ((row * 128 + (kc * 32 + lg * 8) * 2) ^ ((row & 7) << 4)));
      }
#pragma unroll
      for (int ni = 0; ni < 4; ++ni) {
        int row = wn * 64 + ni * 16 + l15;
        bfr[ni] = *(const bf16x8*)((const char*)Bs +
                   ((row * 128 + (kc * 32 + lg * 8) * 2) ^ ((row & 7) << 4)));
      }
#pragma unroll
      for (int mi = 0; mi < MI; ++mi)
#pragma unroll
        for (int ni = 0; ni < 4; ++ni)
          acc[mi][ni] = __builtin_amdgcn_mfma_f32_16x16x32_bf16(af[mi], bfr[ni], acc[mi][ni], 0, 0, 0);
    }
    __syncthreads();
  }

#pragma unroll
  for (int mi = 0; mi < MI; ++mi)
#pragma unroll
    for (int rr = 0; rr < 4; ++rr) {
      int row = bm + wm * (BMT / 2) + mi * 16 + lg * 4 + rr;
      bool v2 = (row < MOE_ROWS) && ((row < CAP) ? (row < c0) : ((row - CAP) < c1));
      if (v2) {
#pragma unroll
        for (int ni = 0; ni < 4; ++ni) {
          int col = bn + wn * 64 + ni * 16 + l15;
          hid[((size_t)e * MOE_ROWS + row) * FF + col] =
              f2bf(geluf(acc[mi][ni][rr] + b1all[e * FF + col]));
        }
      }
    }
}

// ---- MoE variant 2: out[tok] += topp * (hid @ w2T[e] + b2[e]), BMT tile ----
template <int BMT>
__global__ __launch_bounds__(256) void moe_mgemm2_kernel(const ushort_t* __restrict__ hid,
                                                         const ushort_t* __restrict__ w2T,
                                                         const float* __restrict__ b2all,
                                                         const int* __restrict__ list,
                                                         const int* __restrict__ cnt,
                                                         const float* __restrict__ topp,
                                                         ushort_t* __restrict__ out) {
  constexpr int MI = BMT / 32;
  __shared__ ushort_t As[BMT * 64];
  __shared__ ushort_t Bs[128 * 64];
  const int e = blockIdx.z;
  const int c0 = cnt[e * 2 + 0], c1 = cnt[e * 2 + 1];
  const ushort_t* Bw = w2T + (size_t)e * FF * Dd;
  const int tid = threadIdx.x;
  const int l = tid & 63, l15 = l & 15, lg = l >> 4;
  const int w = tid >> 6;
  const int wm = w >> 1, wn = w & 1;
  const int bm = blockIdx.x * BMT, bn = blockIdx.y * 128;
  const int srowA = w * (BMT / 4) + (l >> 3);
  const int srowB = w * 32 + (l >> 3);
  const int scc = ((l & 7) ^ (l >> 3)) * 8;

  f32x4 acc[MI][4];
#pragma unroll
  for (int i = 0; i < MI; ++i)
#pragma unroll
    for (int j = 0; j < 4; ++j) acc[i][j] = (f32x4){0.f, 0.f, 0.f, 0.f};

  const ushort_t* agp[MI];
  const ushort_t* bgp[4];
#pragma unroll
  for (int j = 0; j < MI; ++j) {
    int r = bm + srowA + j * 8; if (r > MOE_ROWS - 1) r = MOE_ROWS - 1;
    agp[j] = hid + ((size_t)e * MOE_ROWS + r) * FF + scc;
  }
#pragma unroll
  for (int j = 0; j < 4; ++j)
    bgp[j] = Bw + (size_t)(bn + srowB + j * 8) * FF + scc;

  for (int k0 = 0; k0 < FF; k0 += 64) {
#pragma unroll
    for (int j = 0; j < MI; ++j)
      glds16(agp[j] + k0, (char*)As + w * (BMT * 32) + j * 1024);
#pragma unroll
    for (int j = 0; j < 4; ++j)
      glds16(bgp[j] + k0, (char*)Bs + w * 4096 + j * 1024);
    __syncthreads();
#pragma unroll
    for (int kc = 0; kc < 2; ++kc) {
      bf16x8 af[MI], bfr[4];
#pragma unroll
      for (int mi = 0; mi < MI; ++mi) {
        int row = wm * (BMT / 2) + mi * 16 + l15;
        af[mi] = *(const bf16x8*)((const char*)As +
                   ((row * 128 + (kc * 32 + lg * 8) * 2) ^ ((row & 7) << 4)));
      }
#pragma unroll
      for (int ni = 0; ni < 4; ++ni) {
        int row = wn * 64 + ni * 16 + l15;
        bfr[ni] = *(const bf16x8*)((const char*)Bs +
                   ((row * 128 + (kc * 32 + lg * 8) * 2) ^ ((row & 7) << 4)));
      }
#pragma unroll
      for (int mi = 0; mi < MI; ++mi)
#pragma unroll
        for (int ni = 0; ni < 4; ++ni)
          acc[mi][ni] = __builtin_amdgcn_mfma_f32_16x16x32_bf16(af[mi], bfr[ni], acc[mi][ni], 0, 0, 0);
    }
    __syncthreads();
  }

#pragma unroll
  for (int mi = 0; mi < MI; ++mi)
#pragma unroll
    for (int rr = 0; rr < 4; ++rr) {
      int row = bm + wm * (BMT / 2) + mi * 16 + lg * 4 + rr;
      bool v2 = (row < MOE_ROWS) && ((row < CAP) ? (row < c0) : ((row - CAP) < c1));
      if (v2) {
        int tok = list[e * MOE_ROWS + row];
        int b = tok >> 11, s = tok & (Ss - 1);
        float tp = topp[tok];
#pragma unroll
        for (int ni = 0; ni < 4; ++ni) {
          int col = bn + wn * 64 + ni * 16 + l15;
          size_t oidx = (size_t)(b * S1 + s + 1) * Dd + col;
          out[oidx] = f2bf(bf2f(out[oidx]) + tp * (acc[mi][ni][rr] + b2all[e * Dd + col]));
        }
      }
    }
}

// ---------------- cls rows fill (rows 0 and S1) -----------------------------
__global__ __launch_bounds__(256) void cls_fill_kernel(const float* __restrict__ cls,
                                                       ushort_t* __restrict__ h) {
  int i = threadIdx.x;
  uint_t pk = (uint_t)f2bf(cls[i * 2]) | ((uint_t)f2bf(cls[i * 2 + 1]) << 16);
  *(uint_t*)(h + i * 2) = pk;
  *(uint_t*)(h + (size_t)S1 * Dd + i * 2) = pk;
}

// ---------------- wave-per-row LayerNorm (bf16 in/out, fp32 stats) ----------
template <int EPL>
__global__ __launch_bounds__(256) void ln_wave_kernel(const ushort_t* __restrict__ in,
                                                      const ushort_t* __restrict__ addv,
                                                      const float* __restrict__ g,
                                                      const float* __restrict__ bvec,
                                                      ushort_t* __restrict__ out,
                                                      ushort_t* __restrict__ out2,
                                                      int nrows) {
  constexpr int N = 64 * EPL;
  const int row = blockIdx.x * 4 + (threadIdx.x >> 6);
  const int lane = threadIdx.x & 63;
  if (row >= nrows) return;
  const size_t base = (size_t)row * N + lane * EPL;
  float xf[EPL];
  float s1 = 0.f, s2 = 0.f;
#pragma unroll
  for (int c = 0; c < EPL / 8; ++c) {
    bf16x8 x8 = *(const bf16x8*)(in + base + c * 8);
#pragma unroll
    for (int j = 0; j < 8; ++j) {
      float v = bf2f((ushort_t)x8[j]);
      xf[c * 8 + j] = v;
      s1 += v; s2 += v * v;
    }
  }
  s1 = wsum(s1); s2 = wsum(s2);
  float mean = s1 * (1.0f / N);
  float var = s2 * (1.0f / N) - mean * mean;
  float rstd = rsqrtf(var + 1e-5f);
#pragma unroll
  for (int c = 0; c < EPL / 8; ++c) {
    bf16x8 a8;
    if (addv) a8 = *(const bf16x8*)(addv + base + c * 8);
    bf16x8 o8;
#pragma unroll
    for (int j = 0; j < 8; ++j) {
      int col = lane * EPL + c * 8 + j;
      float v = (xf[c * 8 + j] - mean) * rstd * g[col] + bvec[col];
      if (addv) v += bf2f((ushort_t)a8[j]);
      o8[j] = (short)f2bf(v);
    }
    *(bf16x8*)(out + base + c * 8) = o8;
    if (out2) *(bf16x8*)(out2 + base + c * 8) = o8;
  }
}

// ---------------- fused double-LN: out = LN2(LN1(in)+addv) ------------------
__global__ __launch_bounds__(256) void ln2_wave_kernel(const ushort_t* __restrict__ in,
                                                       const ushort_t* __restrict__ addv,
                                                       const float* __restrict__ g1,
                                                       const float* __restrict__ b1,
                                                       const float* __restrict__ g2,
                                                       const float* __restrict__ b2,
                                                       ushort_t* __restrict__ out,
                                                       ushort_t* __restrict__ out2,
                                                       int nrows) {
  constexpr int N = 512;
  const int row = blockIdx.x * 4 + (threadIdx.x >> 6);
  const int lane = threadIdx.x & 63;
  if (row >= nrows) return;
  const size_t base = (size_t)row * N + lane * 8;
  bf16x8 x8 = *(const bf16x8*)(in + base);
  bf16x8 a8 = *(const bf16x8*)(addv + base);
  float xf[8];
  float s1 = 0.f, s2 = 0.f;
#pragma unroll
  for (int j = 0; j < 8; ++j) {
    float v = bf2f((ushort_t)x8[j]);
    xf[j] = v; s1 += v; s2 += v * v;
  }
  s1 = wsum(s1); s2 = wsum(s2);
  float mean = s1 * (1.0f / N);
  float rstd = rsqrtf(s2 * (1.0f / N) - mean * mean + 1e-5f);
  float vf[8];
  float t1 = 0.f, t2 = 0.f;
#pragma unroll
  for (int j = 0; j < 8; ++j) {
    int col = lane * 8 + j;
    float v = (xf[j] - mean) * rstd * g1[col] + b1[col] + bf2f((ushort_t)a8[j]);
    vf[j] = v; t1 += v; t2 += v * v;
  }
  t1 = wsum(t1); t2 = wsum(t2);
  float mean2 = t1 * (1.0f / N);
  float rstd2 = rsqrtf(t2 * (1.0f / N) - mean2 * mean2 + 1e-5f);
  bf16x8 o8;
#pragma unroll
  for (int j = 0; j < 8; ++j) {
    int col = lane * 8 + j;
    o8[j] = (short)f2bf((vf[j] - mean2) * rstd2 * g2[col] + b2[col]);
  }
  *(bf16x8*)(out + base) = o8;
  if (out2) *(bf16x8*)(out2 + base) = o8;
}

// ---------------- MFMA bf16 flash attention -------------------------------
// swapped-QK (lane-local q row), defer-max, 128-key iterations,
// K staged via glds16 (pre-swizzled source), V transposed in LDS.
// Invalid keys (only iter 16) are clamped at stage and masked in S (P=0).
__global__ __launch_bounds__(256) void attn_mfma_kernel(const ushort_t* __restrict__ qkv,
                                                        ushort_t* __restrict__ o) {
  __shared__ ushort_t Ksh[128 * 64];  // [k][d], row=128B, swz byte^=(r&7)<<4
  __shared__ ushort_t Vt[64 * 128];   // [d][k], row=256B, swz byte^=(d&7)<<4
  const int tid = threadIdx.x;
  const int w = tid >> 6, l = tid & 63;
  const int l15 = l & 15, lg = l >> 4;
  const int hh = blockIdx.y, b = blockIdx.z;
  const int qblk = blockIdx.x * 64;
  const size_t rbase = (size_t)b * S1 * 1536;
  const float CEXP = 0.125f * 1.4426950408889634f;

  bf16x8 aq[2];
  {
    int qr = qblk + w * 16 + l15;
    const ushort_t* qp = qkv + rbase + (size_t)qr * 1536 + hh * 64;
#pragma unroll
    for (int dc = 0; dc < 2; ++dc)
      aq[dc] = (qr < S1) ? *(const bf16x8*)(qp + dc * 32 + lg * 8)
                         : (bf16x8){0, 0, 0, 0, 0, 0, 0, 0};
  }

  f32x4 ovac[4];
#pragma unroll
  for (int dt = 0; dt < 4; ++dt) ovac[dt] = (f32x4){0.f, 0.f, 0.f, 0.f};
  float m_r = -1e30f, l_r = 0.f;

  const int kcc = ((l & 7) ^ (l >> 3)) * 8;          // K glds16 source chunk
  const int krloc = w * 32 + (l >> 3);               // K local row base
  const int sv_k0 = (tid & 63) * 2, sv_d0 = (tid >> 6) * 16;  // V staging

  for (int it = 0; it < 17; ++it) {
    // ---- stage K via glds16 (4 calls/wave = 32 rows) ----
    {
      int rb = it * 128 + krloc;
#pragma unroll
      for (int pass = 0; pass < 4; ++pass) {
        int key = rb + pass * 8;
        if (key > S1 - 1) key = S1 - 1;              // clamp; masked in S
        glds16(qkv + rbase + (size_t)key * 1536 + 512 + hh * 64 + kcc,
               (char*)Ksh + w * 4096 + pass * 1024);
      }
    }
    // ---- stage V transposed (pack key pairs; clamped, P-masked) ----
    {
      int key0 = it * 128 + sv_k0;
      int k0c = (key0 > S1 - 1) ? S1 - 1 : key0;
      int k1c = (key0 + 1 > S1 - 1) ? S1 - 1 : key0 + 1;
      const ushort_t* vp0 = qkv + rbase + (size_t)k0c * 1536 + 1024 + hh * 64 + sv_d0;
      const ushort_t* vp1 = qkv + rbase + (size_t)k1c * 1536 + 1024 + hh * 64 + sv_d0;
      bf16x8 va0 = *(const bf16x8*)(vp0), va1 = *(const bf16x8*)(vp0 + 8);
      bf16x8 vb0 = *(const bf16x8*)(vp1), vb1 = *(const bf16x8*)(vp1 + 8);
#pragma unroll
      for (int i = 0; i < 8; ++i) {
        int d0 = sv_d0 + i, d1 = sv_d0 + 8 + i;
        uint_t p0 = (uint_t)(ushort_t)va0[i] | ((uint_t)(ushort_t)vb0[i] << 16);
        uint_t p1 = (uint_t)(ushort_t)va1[i] | ((uint_t)(ushort_t)vb1[i] << 16);
        *(uint_t*)((char*)Vt + ((d0 * 256 + sv_k0 * 2) ^ ((d0 & 7) << 4))) = p0;
        *(uint_t*)((char*)Vt + ((d1 * 256 + sv_k0 * 2) ^ ((d1 & 7) << 4))) = p1;
      }
    }
    __syncthreads();

    // ---- S^T = K·Q^T (8 k-tiles) ----
    f32x4 s[8];
    __builtin_amdgcn_s_setprio(1);
#pragma unroll
    for (int kt = 0; kt < 8; ++kt) {
      f32x4 acc = (f32x4){0.f, 0.f, 0.f, 0.f};
      const int krow = kt * 16 + l15;
      const int rswz = (krow & 7) << 4;
#pragma unroll
      for (int dc = 0; dc < 2; ++dc) {
        bf16x8 kb = *(const bf16x8*)((const char*)Ksh + (((krow * 64 + dc * 32 + lg * 8) * 2) ^ rswz));
        acc = __builtin_amdgcn_mfma_f32_16x16x32_bf16(kb, aq[dc], acc, 0, 0, 0);
      }
      s[kt] = acc;
    }
    __builtin_amdgcn_s_setprio(0);
    if (it == 16) {          // keys 2048..2175; only 2048 valid
#pragma unroll
      for (int kt = 0; kt < 8; ++kt)
#pragma unroll
        for (int r = 0; r < 4; ++r)
          if (2048 + kt * 16 + lg * 4 + r >= S1) s[kt][r] = -1e30f;
    }

    // ---- online softmax over 128 keys (lane-local q row) ----
    f32x4 m4 = s[0];
#pragma unroll
    for (int kt = 1; kt < 8; ++kt)
#pragma unroll
      for (int r = 0; r < 4; ++r) m4[r] = fmaxf(m4[r], s[kt][r]);
    float mx = fmaxf(fmaxf(m4[0], m4[1]), fmaxf(m4[2], m4[3]));
    mx = fmaxf(mx, __shfl_xor(mx, 16));
    mx = fmaxf(mx, __shfl_xor(mx, 32));
    if (!__all(mx <= m_r + 8.0f)) {                  // defer-max (T13)
      float mn = fmaxf(m_r, mx);
      float fac = __builtin_amdgcn_exp2f((m_r - mn) * CEXP);
      m_r = mn;
      float facq[4];
#pragma unroll
      for (int r = 0; r < 4; ++r) facq[r] = __shfl(fac, lg * 4 + r);
#pragma unroll
      for (int dt = 0; dt < 4; ++dt)
#pragma unroll
        for (int r = 0; r < 4; ++r) ovac[dt][r] *= facq[r];
      l_r *= fac;
    }
    float mc = m_r * CEXP;
    float rs = 0.f;
#pragma unroll
    for (int kt = 0; kt < 8; ++kt)
#pragma unroll
      for (int r = 0; r < 4; ++r) {
        float pv = __builtin_amdgcn_exp2f(s[kt][r] * CEXP - mc);
        s[kt][r] = pv;
        rs += pv;
      }
    rs += __shfl_xor(rs, 16);
    rs += __shfl_xor(rs, 32);
    l_r += rs;

    // ---- pack P to bf16 pairs ----
    uint_t pk[8][2];
#pragma unroll
    for (int kt = 0; kt < 8; ++kt) {
      pk[kt][0] = (uint_t)f2bf(s[kt][0]) | ((uint_t)f2bf(s[kt][1]) << 16);
      pk[kt][1] = (uint_t)f2bf(s[kt][2]) | ((uint_t)f2bf(s[kt][3]) << 16);
    }

    // ---- in-register transpose: P -> PV A-frags (kh 0..3) ----
    bf16x8 pa[4];
#pragma unroll
    for (int kh = 0; kh < 4; ++kh) {
      union { uint_t u[4]; bf16x8 v; } cu;
#pragma unroll
      for (int wd = 0; wd < 4; ++wd) {
        int src = (((2 * lg + (wd >> 1)) & 3) << 4) + l15;
        uint_t c0 = (uint_t)__shfl((int)pk[kh * 2 + 0][wd & 1], src);
        uint_t c1 = (uint_t)__shfl((int)pk[kh * 2 + 1][wd & 1], src);
        cu.u[wd] = (lg & 2) ? c1 : c0;
      }
      pa[kh] = cu.v;
    }

    // ---- O += P @ V ----
    __builtin_amdgcn_s_setprio(1);
#pragma unroll
    for (int kh = 0; kh < 4; ++kh)
#pragma unroll
      for (int dt = 0; dt < 4; ++dt) {
        const int vrow = dt * 16 + l15;
        bf16x8 vb = *(const bf16x8*)((const char*)Vt +
                      (((vrow * 256 + (kh * 32 + lg * 8) * 2)) ^ ((vrow & 7) << 4)));
        ovac[dt] = __builtin_amdgcn_mfma_f32_16x16x32_bf16(pa[kh], vb, ovac[dt], 0, 0, 0);
      }
    __builtin_amdgcn_s_setprio(0);
    __syncthreads();
  }

  float invq[4];
#pragma unroll
  for (int r = 0; r < 4; ++r) invq[r] = 1.0f / __shfl(l_r, lg * 4 + r);
#pragma unroll
  for (int r = 0; r < 4; ++r) {
    int qq = qblk + w * 16 + lg * 4 + r;
    if (qq < S1) {
      ushort_t* orow = o + (size_t)(b * S1 + qq) * Dd + hh * 64;
#pragma unroll
      for (int dt = 0; dt < 4; ++dt) orow[dt * 16 + l15] = f2bf(ovac[dt][r] * invq[r]);
    }
  }
}

// ---------------- gate softmax + top1 routing info (bf16 h) -----------------
__global__ __launch_bounds__(256) void gate_kernel(const ushort_t* __restrict__ h2,
                                                   const float* __restrict__ gw,
                                                   float* __restrict__ gate_out,
                                                   float* __restrict__ topp,
                                                   int* __restrict__ idx) {
  int t = blockIdx.x * 4 + (threadIdx.x >> 6);
  int lane = threadIdx.x & 63;
  if (t >= NTOK) return;
  int b = t >> 11, s = t & (Ss - 1);
  const ushort_t* hr = h2 + (size_t)(b * S1 + s + 1) * Dd;
  bf16x8 h8 = *(const bf16x8*)(hr + lane * 8);
  float acc[6] = {};
#pragma unroll
  for (int j = 0; j < 8; ++j) {
    int d = lane * 8 + j;
    float xv = bf2f((ushort_t)h8[j]);
    const float* g = gw + (size_t)d * Ee;
#pragma unroll
    for (int e = 0; e < 6; ++e) acc[e] += xv * g[e];
  }
#pragma unroll
  for (int e = 0; e < 6; ++e) acc[e] = wsum(acc[e]);
  if (lane == 0) {
    float mx = acc[0];
#pragma unroll
    for (int e = 1; e < 6; ++e) mx = fmaxf(mx, acc[e]);
    float ex[6], sum = 0.f;
#pragma unroll
    for (int e = 0; e < 6; ++e) { ex[e] = __expf(acc[e] - mx); sum += ex[e]; }
    float invs = 1.0f / sum;
    int best = 0; float bp = ex[0];
#pragma unroll
    for (int e = 1; e < 6; ++e) { if (ex[e] > bp) { bp = ex[e]; best = e; } }
#pragma unroll
    for (int e = 0; e < 6; ++e) gate_out[(size_t)t * Ee + e] = ex[e] * invs;
    topp[t] = bp * invs;
    idx[t] = best;
  }
}

// ---------------- capacity-limited top-1 router (parallel scan) -------------
__global__ __launch_bounds__(256) void route_kernel(const int* __restrict__ idx,
                                                    int* __restrict__ list,
                                                    int* __restrict__ cnt) {
  __shared__ int cnts[256];
  __shared__ int tot;
  const int e = blockIdx.x, b = blockIdx.y;
  const int tid = threadIdx.x;
  const int s0 = tid * 8;
  int loc[8];
  int c = 0;
#pragma unroll
  for (int j = 0; j < 8; ++j) {
    int t = b * Ss + s0 + j;
    if (idx[t] == e) loc[c++] = t;
  }
  cnts[tid] = c;
  __syncthreads();
  if (tid == 0) {
    int run = 0;
    for (int i = 0; i < 256; ++i) { int v = cnts[i]; cnts[i] = run; run += v; }
    tot = run;
  }
  __syncthreads();
  int base = cnts[tid];
  for (int j = 0; j < c; ++j) {
    int pos = base + j;
    if (pos < CAP) list[e * MOE_ROWS + b * CAP + pos] = loc[j];
  }
  if (tid == 0) cnt[e * Bb + b] = (tot < CAP) ? tot : CAP;
}

// ---------------- cls-token sub-LN FFN, split-K parallel --------------------
__global__ __launch_bounds__(256) void cls_ffn1_kernel(const ushort_t* __restrict__ h2,
                                                       const float* __restrict__ w1,
                                                       const float* __restrict__ b1,
                                                       float* __restrict__ chid) {
  __shared__ float hrow[Dd];
  __shared__ float red[8][32];
  const int b = blockIdx.y, tid = threadIdx.x;
  const int cl = tid & 31, kp = tid >> 5;
  const int col = blockIdx.x * 32 + cl;
  const ushort_t* hr = h2 + (size_t)(b * S1) * Dd;
  hrow[tid] = bf2f(hr[tid]);
  hrow[tid + 256] = bf2f(hr[tid + 256]);
  __syncthreads();
  float acc = 0.f;
#pragma unroll 8
  for (int j = 0; j < 64; ++j) {
    int d = kp * 64 + j;
    acc += hrow[d] * w1[(size_t)d * FF + col];
  }
  red[kp][cl] = acc;
  __syncthreads();
  if (kp == 0) {
    float s = b1[col];
#pragma unroll
    for (int i = 0; i < 8; ++i) s += red[i][cl];
    chid[b * FF + col] = geluf(s);
  }
}

__global__ __launch_bounds__(256) void cls_ln_kernel(const float* __restrict__ chid,
                                                     const float* __restrict__ lg,
                                                     const float* __restrict__ lb,
                                                     float* __restrict__ chln) {
  __shared__ float red[8];
  const int b = blockIdx.x, tid = threadIdx.x;
  const float* hr = chid + b * FF;
  float hv[8];
  float s1 = 0.f, s2 = 0.f;
#pragma unroll
  for (int j = 0; j < 8; ++j) {
    hv[j] = hr[tid + j * 256];
    s1 += hv[j]; s2 += hv[j] * hv[j];
  }
  s1 = bsum(s1, red);
  s2 = bsum(s2, red);
  float mean = s1 * (1.0f / FF);
  float rstd = rsqrtf(s2 * (1.0f / FF) - mean * mean + 1e-5f);
#pragma unroll
  for (int j = 0; j < 8; ++j) {
    int k = tid + j * 256;
    chln[b * FF + k] = (hv[j] - mean) * rstd * lg[k] + lb[k];
  }
}

__global__ __launch_bounds__(256) void cls_ffn2_kernel(const float* __restrict__ chln,
                                                       const float* __restrict__ w2,
                                                       const float* __restrict__ b2,
                                                       ushort_t* __restrict__ outbuf) {
  __shared__ float red[8][32];
  const int b = blockIdx.y, tid = threadIdx.x;
  const int cl = tid & 31, kp = tid >> 5;
  const int col = blockIdx.x * 32 + cl;
  const float* hr = chln + b * FF;
  float acc = 0.f;
#pragma unroll 8
  for (int j = 0; j < 256; ++j) {
    int k = kp * 256 + j;
    acc += hr[k] * w2[(size_t)k * Dd + col];
  }
  red[kp][cl] = acc;
  __syncthreads();
  if (kp == 0) {
    float s = b2[col];
#pragma unroll
    for (int i = 0; i < 8; ++i) s += red[i][cl];
    size_t oidx = (size_t)(b * S1) * Dd + col;
    outbuf[oidx] = f2bf(bf2f(outbuf[oidx]) + s);
  }
}

// ---------------- loss ------------------------------------------------------
__global__ __launch_bounds__(256) void loss_part_kernel(const float* __restrict__ gate,
                                                        const int* __restrict__ lbl,
                                                        float* __restrict__ part) {
  __shared__ float red[8];
  int t = blockIdx.x * 256 + threadIdx.x;
  float v = 0.f;
  if (t < NTOK) {
    const float* p = gate + (size_t)t * Ee;
    float sum = p[0] + p[1] + p[2] + p[3];
    float pl = p[lbl[t]];
    v = -logf(pl / sum + 1e-9f);
  }
  v = bsum(v, red);
  if (threadIdx.x == 0) part[blockIdx.x] = v;
}

__global__ void loss_final_kernel(const float* __restrict__ part, float* __restrict__ out) {
  if (threadIdx.x == 0) {
    float s = 0.f;
    for (int i = 0; i < 16; ++i) s += part[i];
    out[NTOK * Ee + Bb * NCc] = s / (float)NTOK;
  }
}

// ---------------- final LN + logits ----------------------------------------
__global__ __launch_bounds__(256) void final_head_kernel(const ushort_t* __restrict__ h,
                                                         const float* __restrict__ g,
                                                         const float* __restrict__ bvec,
                                                         const float* __restrict__ w,
                                                         const float* __restrict__ fb,
                                                         float* __restrict__ out) {
  __shared__ float red[8];
  int b = blockIdx.x, tid = threadIdx.x;
  const ushort_t* hr = h + (size_t)(b * S1) * Dd;
  float x0 = bf2f(hr[tid]), x1 = bf2f(hr[tid + 256]);
  float s1 = bsum(x0 + x1, red);
  float s2 = bsum(x0 * x0 + x1 * x1, red);
  float mean = s1 * (1.0f / Dd);
  float var = s2 * (1.0f / Dd) - mean * mean;
  float rstd = rsqrtf(var + 1e-5f);
  float p0 = (x0 - mean) * rstd * g[tid] + bvec[tid];
  float p1 = (x1 - mean) * rstd * g[tid + 256] + bvec[tid + 256];
  float l0 = p0 * w[tid * 2 + 0] + p1 * w[(tid + 256) * 2 + 0];
  float l1 = p0 * w[tid * 2 + 1] + p1 * w[(tid + 256) * 2 + 1];
  l0 = bsum(l0, red);
  l1 = bsum(l1, red);
  if (tid == 0) {
    out[NTOK * Ee + b * NCc + 0] = l0 + fb[0];
    out[NTOK * Ee + b * NCc + 1] = l1 + fb[1];
  }
}

// ============================================================================
extern "C" void kernel_launch(void* const* d_in, const int* in_sizes, int n_in,
                              void* d_out, int out_size, void* d_ws, size_t ws_size,
                              hipStream_t stream) {
  (void)in_sizes; (void)n_in; (void)out_size; (void)ws_size;
  const float* x       = (const float*)d_in[0];
  const float* protos  = (const float*)d_in[1];
  const float* cls_tok = (const float*)d_in[2];
  const float* fc1_w   = (const float*)d_in[3];
  const float* fc1_b   = (const float*)d_in[4];
  const float* a0_in_w = (const float*)d_in[5];
  const float* a0_in_b = (const float*)d_in[6];
  const float* a0_out_w= (const float*)d_in[7];
  const float* a0_out_b= (const float*)d_in[8];
  const float* n1g0    = (const float*)d_in[9];
  const float* n1b0    = (const float*)d_in[10];
  const float* n2g0    = (const float*)d_in[11];
  const float* n2b0    = (const float*)d_in[12];
  const float* a1_in_w = (const float*)d_in[13];
  const float* a1_in_b = (const float*)d_in[14];
  const float* a1_out_w= (const float*)d_in[15];
  const float* a1_out_b= (const float*)d_in[16];
  const float* n1g1    = (const float*)d_in[17];
  const float* n1b1    = (const float*)d_in[18];
  const float* n2g1    = (const float*)d_in[19];
  const float* n2b1    = (const float*)d_in[20];
  const float* cw1     = (const float*)d_in[21];
  const float* cb1     = (const float*)d_in[22];
  const float* clg     = (const float*)d_in[23];
  const float* clb     = (const float*)d_in[24];
  const float* cw2     = (const float*)d_in[25];
  const float* cb2     = (const float*)d_in[26];
  const float* gate_w  = (const float*)d_in[27];
  const float* ew1     = (const float*)d_in[28];
  const float* eb1     = (const float*)d_in[29];
  const float* ew2     = (const float*)d_in[30];
  const float* eb2     = (const float*)d_in[31];
  const float* fw1     = (const float*)d_in[32];
  const float* fb1     = (const float*)d_in[33];
  const float* flg     = (const float*)d_in[34];
  const float* flb     = (const float*)d_in[35];
  const float* fw2     = (const float*)d_in[36];
  const float* fb2     = (const float*)d_in[37];
  const float* ng      = (const float*)d_in[38];
  const float* nb      = (const float*)d_in[39];
  const float* fc2_w   = (const float*)d_in[40];
  const float* fc2_b   = (const float*)d_in[41];
  float* out = (float*)d_out;

  char* base = (char*)d_ws;
  size_t o = 0;
  auto alloc = [&](size_t bytes) -> void* {
    void* p = base + o;
    o += (bytes + 255) & ~(size_t)255;
    return p;
  };
  ushort_t* UB0  = (ushort_t*)alloc((size_t)RR * Dd * 2);
  ushort_t* UB1  = (ushort_t*)alloc((size_t)RR * Dd * 2);
  ushort_t* UB2  = (ushort_t*)alloc((size_t)RR * Dd * 2);
  ushort_t* BIGU = (ushort_t*)alloc((size_t)RR * FF * 2);
  ushort_t* XB   = (ushort_t*)alloc((size_t)NTOK * DIN * 2);
  ushort_t* WQ0  = (ushort_t*)alloc((size_t)3 * Dd * Dd * 2);
  ushort_t* WO0  = (ushort_t*)alloc((size_t)Dd * Dd * 2);
  ushort_t* WQ1  = (ushort_t*)alloc((size_t)3 * Dd * Dd * 2);
  ushort_t* WO1  = (ushort_t*)alloc((size_t)Dd * Dd * 2);
  ushort_t* WF1T = (ushort_t*)alloc((size_t)Dd * DIN * 2);
  ushort_t* WE1T = (ushort_t*)alloc((size_t)Ee * FF * Dd * 2);
  ushort_t* WE2T = (ushort_t*)alloc((size_t)Ee * Dd * FF * 2);
  ushort_t* WFW1T= (ushort_t*)alloc((size_t)FF * Dd * 2);
  ushort_t* WFW2T= (ushort_t*)alloc((size_t)Dd * FF * 2);
  float* TOPP = (float*)alloc(NTOK * 4);
  float* PART = (float*)alloc(64 * 4);
  float* CHID = (float*)alloc(Bb * FF * 4);
  float* CHLN = (float*)alloc(Bb * FF * 4);
  int* LBL  = (int*)alloc(NTOK * 4);
  int* IDX  = (int*)alloc(NTOK * 4);
  int* LIST = (int*)alloc(Ee * MOE_ROWS * 4);
  int* CNT  = (int*)alloc(Ee * Bb * 4);

  const int ln_grid = (RR + 3) / 4;

  // ---- one-shot conversions (bf16, unified NxK) ----
  cast5_kernel<<<(C5_T + 255) / 256, 256, 0, stream>>>(
      x, XB, a0_in_w, WQ0, a0_out_w, WO0, a1_in_w, WQ1, a1_out_w, WO1);
  tpose_cast_kernel<<<dim3(DIN / 64, Dd / 64, 1), 256, 0, stream>>>(fc1_w, WF1T, DIN, Dd);
  tpose_cast_kernel<<<dim3(Dd / 64, FF / 64, Ee), 256, 0, stream>>>(ew1, WE1T, Dd, FF);
  tpose_cast_kernel<<<dim3(FF / 64, Dd / 64, Ee), 256, 0, stream>>>(ew2, WE2T, FF, Dd);
  tpose_cast_kernel<<<dim3(Dd / 64, FF / 64, 1), 256, 0, stream>>>(fw1, WFW1T, Dd, FF);
  tpose_cast_kernel<<<dim3(FF / 64, Dd / 64, 1), 256, 0, stream>>>(fw2, WFW2T, FF, Dd);

  // 1. labels
  labels_kernel<<<NTOK / 4, 256, 0, stream>>>(x, protos, LBL);
  // 2. fc1 writes straight into shifted h layout (UB0); cls rows filled apart
  mgemm_kernel<false, true, 64><<<dim3(64, 4), 256, 0, stream>>>(
      XB, DIN, WF1T, DIN, fc1_b, nullptr, UB0, Dd, NTOK, Dd, DIN);
  cls_fill_kernel<<<1, 256, 0, stream>>>(cls_tok, UB0);

  // ---- layer 0 attention ----
  mgemm_kernel<false, false, 64><<<dim3(65, 12), 256, 0, stream>>>(
      UB0, Dd, WQ0, Dd, a0_in_b, nullptr, BIGU, 3 * Dd, RR, 3 * Dd, Dd);
  attn_mfma_kernel<<<dim3(33, Hh, Bb), 256, 0, stream>>>(BIGU, UB1);
  mgemm_kernel<false, false, 64><<<dim3(65, 4), 256, 0, stream>>>(
      UB1, Dd, WO0, Dd, a0_out_b, nullptr, UB2, Dd, RR, Dd, Dd);
  // h2 = LN2(LN1(UB0)+UB2) -> UB0 (+UB2 as h_res), fused
  ln2_wave_kernel<<<ln_grid, 256, 0, stream>>>(UB0, UB2, n1g0, n1b0, n2g0, n2b0, UB0, UB2, RR);

  // ---- cls ffn (split-K), gate, route, moe ----
  cls_ffn1_kernel<<<dim3(FF / 32, Bb), 256, 0, stream>>>(UB0, cw1, cb1, CHID);
  cls_ln_kernel<<<Bb, 256, 0, stream>>>(CHID, clg, clb, CHLN);
  cls_ffn2_kernel<<<dim3(Dd / 32, Bb), 256, 0, stream>>>(CHLN, cw2, cb2, UB2);
  gate_kernel<<<NTOK / 4, 256, 0, stream>>>(UB0, gate_w, out, TOPP, IDX);
  route_kernel<<<dim3(Ee, Bb), 256, 0, stream>>>(IDX, LIST, CNT);
  moe_mgemm1_kernel<64><<<dim3(11, 16, Ee), 256, 0, stream>>>(UB0, WE1T, eb1, LIST, CNT, BIGU);
  moe_mgemm2_kernel<64><<<dim3(11, 4, Ee), 256, 0, stream>>>(BIGU, WE2T, eb2, LIST, CNT, TOPP, UB2);
  loss_part_kernel<<<16, 256, 0, stream>>>(out, LBL, PART);
  loss_final_kernel<<<1, 64, 0, stream>>>(PART, out);

  // ---- layer 1 attention ----
  mgemm_kernel<false, false, 64><<<dim3(65, 12), 256, 0, stream>>>(
      UB2, Dd, WQ1, Dd, a1_in_b, nullptr, BIGU, 3 * Dd, RR, 3 * Dd, Dd);
  attn_mfma_kernel<<<dim3(33, Hh, Bb), 256, 0, stream>>>(BIGU, UB1);
  mgemm_kernel<false, false, 64><<<dim3(65, 4), 256, 0, stream>>>(
      UB1, Dd, WO1, Dd, a1_out_b, nullptr, UB0, Dd, RR, Dd, Dd);
  // h = LN2(LN1(UB2)+UB0) -> UB2, fused
  ln2_wave_kernel<<<ln_grid, 256, 0, stream>>>(UB2, UB0, n1g1, n1b1, n2g1, n2b1, UB2, nullptr, RR);

  // ---- layer 1 FFN (sub-LN) with residual ----
  mgemm_kernel<true, false, 64><<<dim3(65, 16), 256, 0, stream>>>(
      UB2, Dd, WFW1T, Dd, fb1, nullptr, BIGU, FF, RR, FF, Dd);
  ln_wave_kernel<32><<<ln_grid, 256, 0, stream>>>(BIGU, nullptr, flg, flb, BIGU, nullptr, RR);
  mgemm_kernel<false, false, 64><<<dim3(65, 4), 256, 0, stream>>>(
      BIGU, FF, WFW2T, FF, fb2, UB2, UB0, Dd, RR, Dd, FF);

  // ---- head ----
  final_head_kernel<<<Bb, 256, 0, stream>>>(UB0, ng, nb, fc2_w, fc2_b, out);
}